// Round 2
// baseline (7101.057 us; speedup 1.0000x reference)
//
#include <hip/hip_runtime.h>
#include <math.h>

#define B_    4
#define T_    2048
#define D_    1024
#define H_    4
#define DK_   256
#define DV_   512
#define KDIM_ 1024
#define VDIM_ 2048
#define FFN_  4096
#define BT_   8192   // B_*T_

typedef unsigned short bf16;

// ---------------- helpers ----------------

__device__ __forceinline__ float sigmoidf_(float x) { return 1.f / (1.f + expf(-x)); }
__device__ __forceinline__ float siluf_(float x)    { return x / (1.f + expf(-x)); }
__device__ __forceinline__ float geluf_(float x)    { return 0.5f * x * (1.f + erff(x * 0.70710678118654752f)); }

__device__ __forceinline__ float bf2f(bf16 u) {
  union { unsigned int i; float f; } c; c.i = (unsigned int)u << 16; return c.f;
}
__device__ __forceinline__ bf16 f2bf(float f) {
  union { unsigned int i; float f; } c; c.f = f;
  unsigned int r = c.i + 0x7fffu + ((c.i >> 16) & 1u);   // RNE
  return (bf16)(r >> 16);
}

__device__ __forceinline__ float4 load4f(const float* p) { return *(const float4*)p; }
__device__ __forceinline__ float4 load4f(const bf16* p) {
  ushort4 u = *(const ushort4*)p;
  return make_float4(bf2f(u.x), bf2f(u.y), bf2f(u.z), bf2f(u.w));
}
__device__ __forceinline__ void store4(float* p, float4 v) { *(float4*)p = v; }
__device__ __forceinline__ void store4(bf16* p, float4 v) {
  ushort4 u; u.x = f2bf(v.x); u.y = f2bf(v.y); u.z = f2bf(v.z); u.w = f2bf(v.w);
  *(ushort4*)p = u;
}

// block of exactly 256 threads (4 waves); returns same sum to all threads
__device__ __forceinline__ float block_sum256(float v, float* red) {
#pragma unroll
  for (int off = 32; off; off >>= 1) v += __shfl_xor(v, off, 64);
  __syncthreads();
  if ((threadIdx.x & 63) == 0) red[threadIdx.x >> 6] = v;
  __syncthreads();
  return red[0] + red[1] + red[2] + red[3];
}

// ---------------- diagnostic sentinel (ws too small) ----------------

__global__ __launch_bounds__(256) void sentinel_kernel(float* out, int n) {
  int i = blockIdx.x * 256 + threadIdx.x;
  if (i < n) out[i] = 12345.0f;
}

// ---------------- LayerNorm (one row per block) ----------------

__global__ __launch_bounds__(256) void ln_kernel(const float* __restrict__ x,
                                                 const float* __restrict__ w,
                                                 const float* __restrict__ b,
                                                 float* __restrict__ y) {
  __shared__ float red[4];
  int row = blockIdx.x;
  const float* xr = x + (size_t)row * D_;
  float xv[4];
  float s = 0.f;
#pragma unroll
  for (int i = 0; i < 4; i++) { xv[i] = xr[threadIdx.x + 256 * i]; s += xv[i]; }
  float mean = block_sum256(s, red) * (1.f / D_);
  float s2 = 0.f;
#pragma unroll
  for (int i = 0; i < 4; i++) { float d = xv[i] - mean; s2 += d * d; }
  float var = block_sum256(s2, red) * (1.f / D_);
  float inv = rsqrtf(var + 1e-5f);
  float* yr = y + (size_t)row * D_;
#pragma unroll
  for (int i = 0; i < 4; i++) {
    int c = threadIdx.x + 256 * i;
    yr[c] = (xv[i] - mean) * inv * w[c] + b[c];
  }
}

// ---------------- generic GEMM: C = act(A@W [+bias]) [+res] ----------------
// A [M,K] row-major (fp32 or bf16), W [K,N] row-major fp32. 64x64 tile, 4x4/thread.
// flags: 1=add bias[col], 2=gelu, 4=add res[row*N+col] (fp32)

template <typename TA, typename TC>
__global__ __launch_bounds__(256) void gemm64(const TA* __restrict__ A,
                                              const float* __restrict__ W,
                                              const float* __restrict__ bias,
                                              const float* __restrict__ res,
                                              TC* __restrict__ C,
                                              int N, int K, int flags) {
  __shared__ float As[16][68];
  __shared__ float Ws[16][64];
  int bm = blockIdx.y * 64, bn = blockIdx.x * 64;
  int tid = threadIdx.x;
  int tx = tid & 15, ty = tid >> 4;
  int arow = tid >> 2, akq = tid & 3;
  int wkr = tid >> 4, wnq = tid & 15;
  float acc[4][4] = {};
  const TA* aptr = A + (size_t)(bm + arow) * K + akq * 4;
  const float* wptr = W + (size_t)wkr * N + bn + wnq * 4;

  for (int k0 = 0; k0 < K; k0 += 16) {
    float4 av = load4f(aptr + k0);
    float4 wv = *(const float4*)(wptr + (size_t)k0 * N);
    As[akq * 4 + 0][arow] = av.x;
    As[akq * 4 + 1][arow] = av.y;
    As[akq * 4 + 2][arow] = av.z;
    As[akq * 4 + 3][arow] = av.w;
    *(float4*)&Ws[wkr][wnq * 4] = wv;
    __syncthreads();
#pragma unroll
    for (int kk = 0; kk < 16; kk++) {
      float4 a4 = *(const float4*)&As[kk][ty * 4];
      float4 b4 = *(const float4*)&Ws[kk][tx * 4];
      float av_[4] = {a4.x, a4.y, a4.z, a4.w};
      float bv_[4] = {b4.x, b4.y, b4.z, b4.w};
#pragma unroll
      for (int i = 0; i < 4; i++)
#pragma unroll
        for (int j = 0; j < 4; j++) acc[i][j] += av_[i] * bv_[j];
    }
    __syncthreads();
  }

#pragma unroll
  for (int i = 0; i < 4; i++) {
    int row = bm + ty * 4 + i;
    int col = bn + tx * 4;
    float vv[4] = {acc[i][0], acc[i][1], acc[i][2], acc[i][3]};
    if (flags & 1) {
#pragma unroll
      for (int j = 0; j < 4; j++) vv[j] += bias[col + j];
    }
    if (flags & 2) {
#pragma unroll
      for (int j = 0; j < 4; j++) vv[j] = geluf_(vv[j]);
    }
    if (flags & 4) {
      float4 r = *(const float4*)&res[(size_t)row * N + col];
      vv[0] += r.x; vv[1] += r.y; vv[2] += r.z; vv[3] += r.w;
    }
    store4(&C[(size_t)row * N + col], make_float4(vv[0], vv[1], vv[2], vv[3]));
  }
}

// ---------------- fused Wa/Wb projections -> g, beta (one row per block) ----------------

__global__ __launch_bounds__(256) void ab_kernel(const float* __restrict__ normed,
                                                 const float* __restrict__ Wa,
                                                 const float* __restrict__ Wb,
                                                 const float* __restrict__ A_log,
                                                 const float* __restrict__ dt_bias,
                                                 float* __restrict__ g,
                                                 float* __restrict__ beta) {
  __shared__ float red[4];
  int row = blockIdx.x;
  const float* xr = normed + (size_t)row * D_;
  float aacc[4] = {}, bacc[4] = {};
#pragma unroll
  for (int i = 0; i < 4; i++) {
    int d = threadIdx.x + 256 * i;
    float xv = xr[d];
    float4 wa = *(const float4*)&Wa[d * 4];
    float4 wb = *(const float4*)&Wb[d * 4];
    aacc[0] += xv * wa.x; aacc[1] += xv * wa.y; aacc[2] += xv * wa.z; aacc[3] += xv * wa.w;
    bacc[0] += xv * wb.x; bacc[1] += xv * wb.y; bacc[2] += xv * wb.z; bacc[3] += xv * wb.w;
  }
  float sa[4], sb[4];
#pragma unroll
  for (int h = 0; h < 4; h++) {
    sa[h] = block_sum256(aacc[h], red);
    sb[h] = block_sum256(bacc[h], red);
  }
  if (threadIdx.x < 4) {
    int h = threadIdx.x;
    float xa = sa[h] + dt_bias[h];
    float sp = (xa > 20.f) ? xa : log1pf(expf(xa));
    g[row * 4 + h] = -expf(A_log[h]) * sp;
    beta[row * 4 + h] = sigmoidf_(sb[h]);
  }
}

// ---------------- causal depthwise conv(4) + SiLU + per-head L2 norm (q/k) ----------------
// one block per (b,t,h); 256 threads = DK channels. out: bf16

__global__ __launch_bounds__(256) void conv_qk_kernel(const float* __restrict__ pre,
                                                      const float* __restrict__ convw,
                                                      bf16* __restrict__ out,
                                                      float scale) {
  __shared__ float red[4];
  int blk = blockIdx.x;
  int h = blk & 3;
  int bt = blk >> 2;
  int t = bt & (T_ - 1);
  int c = h * DK_ + threadIdx.x;
  float y = 0.f;
#pragma unroll
  for (int i = 0; i < 4; i++) {
    int tt = t + i - 3;
    if (tt >= 0) y += pre[(size_t)(bt + i - 3) * KDIM_ + c] * convw[c * 4 + i];
  }
  y = siluf_(y);
  float ss = block_sum256(y * y, red);
  y *= rsqrtf(ss + 1e-6f) * scale;
  out[(size_t)bt * KDIM_ + c] = f2bf(y);
}

// conv + SiLU only, for v. out: bf16

__global__ __launch_bounds__(256) void conv_v_kernel(const float* __restrict__ pre,
                                                     const float* __restrict__ convw,
                                                     bf16* __restrict__ out) {
  int idx = blockIdx.x * 256 + threadIdx.x;
  int c = idx & (VDIM_ - 1);
  int bt = idx >> 11;
  int t = bt & (T_ - 1);
  float y = 0.f;
#pragma unroll
  for (int i = 0; i < 4; i++) {
    int tt = t + i - 3;
    if (tt >= 0) y += pre[(size_t)(bt + i - 3) * VDIM_ + c] * convw[c * 4 + i];
  }
  out[idx] = f2bf(siluf_(y));
}

// ---------------- gated delta rule recurrence ----------------
// grid = B*H*(DV/32) = 256 blocks; block = 256 threads.
// Block owns S[256 x 32] (cols v0..v0+31); thread (kg,vl) owns S[kg*32..+31][v0+vl]. S in fp32 regs.

__global__ __launch_bounds__(256) void delta_kernel(const bf16* __restrict__ q,
                                                    const bf16* __restrict__ k,
                                                    const bf16* __restrict__ v,
                                                    const float* __restrict__ g,
                                                    const float* __restrict__ beta,
                                                    bf16* __restrict__ o) {
  __shared__ float ks[256], qs[256], red[128], red2[128], dm[32];
  int blk = blockIdx.x;
  int chunk = blk & 15;
  int bh = blk >> 4;
  int b = bh >> 2, h = bh & 3;
  int tid = threadIdx.x;
  int kg = tid >> 5, vl = tid & 31;
  int w = tid >> 6, lane = tid & 63;
  int v0 = chunk * 32;

  float S[32];
#pragma unroll
  for (int j = 0; j < 32; j++) S[j] = 0.f;

  const bf16* kb = k + (size_t)b * T_ * KDIM_ + h * DK_;
  const bf16* qb = q + (size_t)b * T_ * KDIM_ + h * DK_;
  const bf16* vb = v + (size_t)b * T_ * VDIM_ + h * DV_ + v0;
  const float* gb = g + (size_t)b * T_ * H_ + h;
  const float* bb = beta + (size_t)b * T_ * H_ + h;
  bf16* ob = o + (size_t)b * T_ * VDIM_ + h * DV_ + v0;

  for (int t = 0; t < T_; t++) {
    ks[tid] = bf2f(kb[(size_t)t * KDIM_ + tid]);
    qs[tid] = bf2f(qb[(size_t)t * KDIM_ + tid]);
    float vt = bf2f(vb[(size_t)t * VDIM_ + vl]);
    float gt = gb[(size_t)t * H_];
    float bt = bb[(size_t)t * H_];
    __syncthreads();                    // (1) ks/qs ready
    float eg = expf(gt);

    float kr[32];
    float mem_p = 0.f;
#pragma unroll
    for (int j = 0; j < 32; j++) { kr[j] = ks[kg * 32 + j]; mem_p += kr[j] * S[j]; }
    mem_p += __shfl_xor(mem_p, 32, 64);
    if (lane < 32) red[w * 32 + lane] = mem_p;
    __syncthreads();                    // (2) red ready
    if (tid < 32) {
      float m = red[tid] + red[32 + tid] + red[64 + tid] + red[96 + tid];
      dm[tid] = (vt - eg * m) * bt;
    }
    __syncthreads();                    // (3) dm ready
    float d = dm[vl];
    float o_p = 0.f;
#pragma unroll
    for (int j = 0; j < 32; j++) {
      S[j] = S[j] * eg + kr[j] * d;
      o_p += qs[kg * 32 + j] * S[j];
    }
    o_p += __shfl_xor(o_p, 32, 64);
    if (lane < 32) red2[w * 32 + lane] = o_p;
    __syncthreads();                    // (4) red2 ready
    if (tid < 32)
      ob[(size_t)t * VDIM_ + tid] = f2bf(red2[tid] + red2[32 + tid] + red2[64 + tid] + red2[96 + tid]);
  }
}

// ---------------- gated RMSNorm: o = rms(o)*o_norm_w*silu(gate), in place (bf16) ----------------

__global__ __launch_bounds__(256) void gated_rms_kernel(bf16* __restrict__ o,
                                                        const bf16* __restrict__ gate,
                                                        const float* __restrict__ onw) {
  __shared__ float red[4];
  int blk = blockIdx.x;
  int h = blk & 3;
  int bt = blk >> 2;
  size_t base = (size_t)bt * VDIM_ + h * DV_;
  int tid = threadIdx.x;
  float o1 = bf2f(o[base + tid]), o2 = bf2f(o[base + tid + 256]);
  float ss = block_sum256(o1 * o1 + o2 * o2, red);
  float s = rsqrtf(ss * (1.f / DV_) + 1e-5f);
  float g1 = bf2f(gate[base + tid]), g2 = bf2f(gate[base + tid + 256]);
  o[base + tid]       = f2bf(o1 * s * onw[tid] * siluf_(g1));
  o[base + tid + 256] = f2bf(o2 * s * onw[tid + 256] * siluf_(g2));
}

// ---------------- launch ----------------

extern "C" void kernel_launch(void* const* d_in, const int* in_sizes, int n_in,
                              void* d_out, int out_size, void* d_ws, size_t ws_size,
                              hipStream_t stream) {
  const float* x        = (const float*)d_in[0];
  const float* Wq       = (const float*)d_in[1];
  const float* Wk       = (const float*)d_in[2];
  const float* Wv       = (const float*)d_in[3];
  const float* Wa       = (const float*)d_in[4];
  const float* Wb       = (const float*)d_in[5];
  const float* Wg       = (const float*)d_in[6];
  const float* conv_q_w = (const float*)d_in[7];
  const float* conv_k_w = (const float*)d_in[8];
  const float* conv_v_w = (const float*)d_in[9];
  const float* A_log    = (const float*)d_in[10];
  const float* dt_bias  = (const float*)d_in[11];
  const float* o_norm_w = (const float*)d_in[12];
  const float* Wo       = (const float*)d_in[13];
  const float* ln1_w    = (const float*)d_in[14];
  const float* ln1_b    = (const float*)d_in[15];
  const float* ln2_w    = (const float*)d_in[16];
  const float* ln2_b    = (const float*)d_in[17];
  const float* ffn_w1   = (const float*)d_in[18];
  const float* ffn_b1   = (const float*)d_in[19];
  const float* ffn_w2   = (const float*)d_in[20];
  const float* ffn_b2   = (const float*)d_in[21];

  float* ws = (float*)d_ws;
  const size_t An = (size_t)BT_ * D_;          // 8,388,608 floats = 32 MB

  // required arena: 7A floats + g/beta vectors
  size_t required = (7 * An + 2 * (size_t)BT_ * H_ + 64) * sizeof(float);   // ~224.3 MB
  if (ws_size < required) {
    // diagnostic fallback: ws too small — write sentinel so the bench reports absmax ~12344
    sentinel_kernel<<<(out_size + 255) / 256, 256, 0, stream>>>((float*)d_out, out_size);
    return;
  }

  // arena layout (float offsets):
  float* normed = ws;                          // [0, A)        fp32
  float* pre    = ws + An;                     // [A, 3A)       fp32 scratch (qpre/kpre/vpre)
  bf16*  q16    = (bf16*)(ws + 3 * An);        // [3A, 3.5A)
  bf16*  k16    = (bf16*)(ws + 3 * An + An / 2);// [3.5A, 4A)
  bf16*  v16    = (bf16*)(ws + 4 * An);        // [4A, 5A)
  bf16*  g16    = (bf16*)(ws + 5 * An);        // [5A, 6A)
  bf16*  o16    = (bf16*)(ws + 6 * An);        // [6A, 7A)
  float* gvec   = ws + 7 * An;                 // 32768 floats
  float* bvec   = gvec + (size_t)BT_ * H_;
  float* x2     = ws + An;                     // reuse pre [A,2A) after convs done
  float* hb     = ws + 2 * An;                 // reuse [2A,3A)
  float* ffn1   = ws + 3 * An;                 // reuse q16/k16 region: 1024*4096 fp32 = 0.5A

  // 1) LN1
  ln_kernel<<<BT_, 256, 0, stream>>>(x, ln1_w, ln1_b, normed);

  // 2) q/k/v/gate projections + convs (pre scratch reused serially on stream)
  gemm64<float, float><<<dim3(KDIM_ / 64, BT_ / 64), 256, 0, stream>>>(normed, Wq, nullptr, nullptr, pre, KDIM_, D_, 0);
  conv_qk_kernel<<<BT_ * H_, 256, 0, stream>>>(pre, conv_q_w, q16, 0.0625f);
  gemm64<float, float><<<dim3(KDIM_ / 64, BT_ / 64), 256, 0, stream>>>(normed, Wk, nullptr, nullptr, pre, KDIM_, D_, 0);
  conv_qk_kernel<<<BT_ * H_, 256, 0, stream>>>(pre, conv_k_w, k16, 1.0f);
  gemm64<float, float><<<dim3(VDIM_ / 64, BT_ / 64), 256, 0, stream>>>(normed, Wv, nullptr, nullptr, pre, VDIM_, D_, 0);
  conv_v_kernel<<<(BT_ * VDIM_) / 256, 256, 0, stream>>>(pre, conv_v_w, v16);
  gemm64<float, bf16><<<dim3(VDIM_ / 64, BT_ / 64), 256, 0, stream>>>(normed, Wg, nullptr, nullptr, g16, VDIM_, D_, 0);
  ab_kernel<<<BT_, 256, 0, stream>>>(normed, Wa, Wb, A_log, dt_bias, gvec, bvec);

  // 3) gated delta rule
  delta_kernel<<<B_ * H_ * (DV_ / 32), 256, 0, stream>>>(q16, k16, v16, gvec, bvec, o16);

  // 4) gated RMSNorm (in place)
  gated_rms_kernel<<<BT_ * H_, 256, 0, stream>>>(o16, g16, o_norm_w);

  // 5) x2 = x + o @ Wo
  gemm64<bf16, float><<<dim3(D_ / 64, BT_ / 64), 256, 0, stream>>>(o16, Wo, nullptr, x, x2, D_, VDIM_, 4);

  // 6) LN2
  ln_kernel<<<BT_, 256, 0, stream>>>(x2, ln2_w, ln2_b, hb);

  // 7) FFN, chunked over rows (1024 rows/chunk) to cap the 16 MB intermediate
  for (int r0 = 0; r0 < BT_; r0 += 1024) {
    gemm64<float, float><<<dim3(FFN_ / 64, 1024 / 64), 256, 0, stream>>>(hb + (size_t)r0 * D_, ffn_w1, ffn_b1, nullptr, ffn1, FFN_, D_, 1 | 2);
    gemm64<float, float><<<dim3(D_ / 64, 1024 / 64), 256, 0, stream>>>(ffn1, ffn_w2, ffn_b2, x2 + (size_t)r0 * D_, (float*)d_out + (size_t)r0 * D_, D_, FFN_, 1 | 4);
  }
}

// Round 3
// 3150.176 us; speedup vs baseline: 2.2542x; 2.2542x over previous
//
#include <hip/hip_runtime.h>
#include <math.h>

#define B_    4
#define T_    2048
#define D_    1024
#define H_    4
#define DK_   256
#define DV_   512
#define KDIM_ 1024
#define VDIM_ 2048
#define FFN_  4096
#define BT_   8192   // B_*T_

typedef unsigned short bf16;
typedef __attribute__((ext_vector_type(8))) short short8;   // MFMA A/B frag (8 bf16)
typedef __attribute__((ext_vector_type(4))) float f32x4;    // MFMA C/D frag

// ---------------- helpers ----------------

__device__ __forceinline__ float sigmoidf_(float x) { return 1.f / (1.f + expf(-x)); }
__device__ __forceinline__ float siluf_(float x)    { return x / (1.f + expf(-x)); }
__device__ __forceinline__ float geluf_(float x)    { return 0.5f * x * (1.f + erff(x * 0.70710678118654752f)); }

__device__ __forceinline__ float bf2f(bf16 u) {
  union { unsigned int i; float f; } c; c.i = (unsigned int)u << 16; return c.f;
}
__device__ __forceinline__ bf16 f2bf(float f) {
  union { unsigned int i; float f; } c; c.f = f;
  unsigned int r = c.i + 0x7fffu + ((c.i >> 16) & 1u);   // RNE
  return (bf16)(r >> 16);
}

// async global->LDS, 16B per lane; lds dest = uniform base + lane*16
__device__ __forceinline__ void gload16(const bf16* g, bf16* l) {
  __builtin_amdgcn_global_load_lds((__attribute__((address_space(1))) const void*)g,
                                   (__attribute__((address_space(3))) void*)l, 16, 0, 0);
}

__device__ __forceinline__ void storeC(float* p, float v) { *p = v; }
__device__ __forceinline__ void storeC(bf16* p, float v)  { *p = f2bf(v); }

// block of exactly 256 threads; returns same sum to all threads
__device__ __forceinline__ float block_sum256(float v, float* red) {
#pragma unroll
  for (int off = 32; off; off >>= 1) v += __shfl_xor(v, off, 64);
  __syncthreads();
  if ((threadIdx.x & 63) == 0) red[threadIdx.x >> 6] = v;
  __syncthreads();
  return red[0] + red[1] + red[2] + red[3];
}

// ---------------- diagnostic sentinel (ws too small) ----------------

__global__ __launch_bounds__(256) void sentinel_kernel(float* out, int n) {
  int i = blockIdx.x * 256 + threadIdx.x;
  if (i < n) out[i] = 12345.0f;
}

// ---------------- LayerNorm (one row per block) -> bf16 out ----------------

__global__ __launch_bounds__(256) void ln_kernel(const float* __restrict__ x,
                                                 const float* __restrict__ w,
                                                 const float* __restrict__ b,
                                                 bf16* __restrict__ y) {
  __shared__ float red[4];
  int row = blockIdx.x;
  const float* xr = x + (size_t)row * D_;
  float xv[4];
  float s = 0.f;
#pragma unroll
  for (int i = 0; i < 4; i++) { xv[i] = xr[threadIdx.x + 256 * i]; s += xv[i]; }
  float mean = block_sum256(s, red) * (1.f / D_);
  float s2 = 0.f;
#pragma unroll
  for (int i = 0; i < 4; i++) { float d = xv[i] - mean; s2 += d * d; }
  float var = block_sum256(s2, red) * (1.f / D_);
  float inv = rsqrtf(var + 1e-5f);
  bf16* yr = y + (size_t)row * D_;
#pragma unroll
  for (int i = 0; i < 4; i++) {
    int c = threadIdx.x + 256 * i;
    yr[c] = f2bf((xv[i] - mean) * inv * w[c] + b[c]);
  }
}

// ---------------- weight convert+transpose: fp32 [K][N] -> bf16 [N][K] ----------------

__global__ __launch_bounds__(256) void convT_kernel(const float* __restrict__ src,
                                                    bf16* __restrict__ dst,
                                                    int K, int N) {
  __shared__ float t[32][33];
  int n0 = blockIdx.x * 32, k0 = blockIdx.y * 32;
  int tx = threadIdx.x & 31, ty = threadIdx.x >> 5;   // ty 0..7
#pragma unroll
  for (int i = 0; i < 4; i++)
    t[ty + i * 8][tx] = src[(size_t)(k0 + ty + i * 8) * N + n0 + tx];
  __syncthreads();
#pragma unroll
  for (int i = 0; i < 4; i++)
    dst[(size_t)(n0 + ty + i * 8) * K + k0 + tx] = f2bf(t[tx][ty + i * 8]);
}

// ---------------- bf16 MFMA GEMM ----------------
// A [M][K] bf16 row-major, Bt [N][K] bf16 row-major (transposed weights).
// 128x128 block tile, BK=32, 4 waves (2x2), each wave 4x4 16x16 tiles.
// flags: 1=add bias[col] (fp32), 2=gelu, 4=add res[row*N+col] (fp32)

template <typename TC>
__global__ __launch_bounds__(256) void gemm_mfma(const bf16* __restrict__ A,
                                                 const bf16* __restrict__ Bt,
                                                 const float* __restrict__ bias,
                                                 const float* __restrict__ res,
                                                 TC* __restrict__ C,
                                                 int N, int K, int flags) {
  __shared__ __align__(16) bf16 As[128 * 32];   // [m][k] 8KB
  __shared__ __align__(16) bf16 Bs[128 * 32];   // [n][k] 8KB
  int tid = threadIdx.x;
  int wave = tid >> 6, lane = tid & 63;
  int bm = blockIdx.y * 128, bn = blockIdx.x * 128;
  int wm = (wave >> 1) * 64, wn = (wave & 1) * 64;
  int lm = lane & 15;        // m (A) / n (B) / col (D)
  int quad = lane >> 4;      // 0..3

  f32x4 acc[4][4];
#pragma unroll
  for (int i = 0; i < 4; i++)
#pragma unroll
    for (int j = 0; j < 4; j++) acc[i][j] = (f32x4){0.f, 0.f, 0.f, 0.f};

  // staging: wave w covers rows [w*32, w*32+32); each instr = 16 rows (64 lanes x 16B)
  int srow = wave * 32 + (lane >> 2);
  int scol = (lane & 3) * 8;
  const bf16* ag = A  + (size_t)(bm + srow) * K + scol;
  const bf16* bg = Bt + (size_t)(bn + srow) * K + scol;
  bf16* al = As + wave * 32 * 32;
  bf16* bl = Bs + wave * 32 * 32;
  const size_t gstep = (size_t)16 * K;

  for (int k0 = 0; k0 < K; k0 += 32) {
    gload16(ag + k0,         al);
    gload16(ag + k0 + gstep, al + 16 * 32);
    gload16(bg + k0,         bl);
    gload16(bg + k0 + gstep, bl + 16 * 32);
    __syncthreads();                        // drains vmcnt, staging visible

    short8 af[4], bf[4];
#pragma unroll
    for (int i = 0; i < 4; i++)
      af[i] = *(const short8*)&As[(wm + i * 16 + lm) * 32 + quad * 8];
#pragma unroll
    for (int j = 0; j < 4; j++)
      bf[j] = *(const short8*)&Bs[(wn + j * 16 + lm) * 32 + quad * 8];
#pragma unroll
    for (int i = 0; i < 4; i++)
#pragma unroll
      for (int j = 0; j < 4; j++)
        acc[i][j] = __builtin_amdgcn_mfma_f32_16x16x32_bf16(af[i], bf[j], acc[i][j], 0, 0, 0);
    __syncthreads();                        // protect LDS before next stage
  }

  // epilogue: D row = quad*4 + r, col = lm  (m89-verified C/D layout)
#pragma unroll
  for (int i = 0; i < 4; i++) {
    int row0 = bm + wm + i * 16 + quad * 4;
#pragma unroll
    for (int j = 0; j < 4; j++) {
      int col = bn + wn + j * 16 + lm;
      float badd = (flags & 1) ? bias[col] : 0.f;
#pragma unroll
      for (int r = 0; r < 4; r++) {
        float v = acc[i][j][r] + badd;
        if (flags & 2) v = geluf_(v);
        if (flags & 4) v += res[(size_t)(row0 + r) * N + col];
        storeC(&C[(size_t)(row0 + r) * N + col], v);
      }
    }
  }
}

// ---------------- fused Wa/Wb projections -> g, beta ----------------

__global__ __launch_bounds__(256) void ab_kernel(const bf16* __restrict__ normed,
                                                 const float* __restrict__ Wa,
                                                 const float* __restrict__ Wb,
                                                 const float* __restrict__ A_log,
                                                 const float* __restrict__ dt_bias,
                                                 float* __restrict__ g,
                                                 float* __restrict__ beta) {
  __shared__ float red[4];
  int row = blockIdx.x;
  const bf16* xr = normed + (size_t)row * D_;
  float aacc[4] = {}, bacc[4] = {};
#pragma unroll
  for (int i = 0; i < 4; i++) {
    int d = threadIdx.x + 256 * i;
    float xv = bf2f(xr[d]);
    float4 wa = *(const float4*)&Wa[d * 4];
    float4 wb = *(const float4*)&Wb[d * 4];
    aacc[0] += xv * wa.x; aacc[1] += xv * wa.y; aacc[2] += xv * wa.z; aacc[3] += xv * wa.w;
    bacc[0] += xv * wb.x; bacc[1] += xv * wb.y; bacc[2] += xv * wb.z; bacc[3] += xv * wb.w;
  }
  float sa[4], sb[4];
#pragma unroll
  for (int h = 0; h < 4; h++) {
    sa[h] = block_sum256(aacc[h], red);
    sb[h] = block_sum256(bacc[h], red);
  }
  if (threadIdx.x < 4) {
    int h = threadIdx.x;
    float xa = sa[h] + dt_bias[h];
    float sp = (xa > 20.f) ? xa : log1pf(expf(xa));
    g[row * 4 + h] = -expf(A_log[h]) * sp;
    beta[row * 4 + h] = sigmoidf_(sb[h]);
  }
}

// ---------------- causal conv(4) + SiLU + per-head L2 norm (q/k) ----------------

__global__ __launch_bounds__(256) void conv_qk_kernel(const float* __restrict__ pre,
                                                      const float* __restrict__ convw,
                                                      bf16* __restrict__ out,
                                                      float scale) {
  __shared__ float red[4];
  int blk = blockIdx.x;
  int h = blk & 3;
  int bt = blk >> 2;
  int t = bt & (T_ - 1);
  int c = h * DK_ + threadIdx.x;
  float y = 0.f;
#pragma unroll
  for (int i = 0; i < 4; i++) {
    int tt = t + i - 3;
    if (tt >= 0) y += pre[(size_t)(bt + i - 3) * KDIM_ + c] * convw[c * 4 + i];
  }
  y = siluf_(y);
  float ss = block_sum256(y * y, red);
  y *= rsqrtf(ss + 1e-6f) * scale;
  out[(size_t)bt * KDIM_ + c] = f2bf(y);
}

__global__ __launch_bounds__(256) void conv_v_kernel(const float* __restrict__ pre,
                                                     const float* __restrict__ convw,
                                                     bf16* __restrict__ out) {
  int idx = blockIdx.x * 256 + threadIdx.x;
  int c = idx & (VDIM_ - 1);
  int bt = idx >> 11;
  int t = bt & (T_ - 1);
  float y = 0.f;
#pragma unroll
  for (int i = 0; i < 4; i++) {
    int tt = t + i - 3;
    if (tt >= 0) y += pre[(size_t)(bt + i - 3) * VDIM_ + c] * convw[c * 4 + i];
  }
  out[idx] = f2bf(siluf_(y));
}

// ---------------- gated delta rule recurrence (unchanged from R2) ----------------

__global__ __launch_bounds__(256) void delta_kernel(const bf16* __restrict__ q,
                                                    const bf16* __restrict__ k,
                                                    const bf16* __restrict__ v,
                                                    const float* __restrict__ g,
                                                    const float* __restrict__ beta,
                                                    bf16* __restrict__ o) {
  __shared__ float ks[256], qs[256], red[128], red2[128], dm[32];
  int blk = blockIdx.x;
  int chunk = blk & 15;
  int bh = blk >> 4;
  int b = bh >> 2, h = bh & 3;
  int tid = threadIdx.x;
  int kg = tid >> 5, vl = tid & 31;
  int w = tid >> 6, lane = tid & 63;
  int v0 = chunk * 32;

  float S[32];
#pragma unroll
  for (int j = 0; j < 32; j++) S[j] = 0.f;

  const bf16* kb = k + (size_t)b * T_ * KDIM_ + h * DK_;
  const bf16* qb = q + (size_t)b * T_ * KDIM_ + h * DK_;
  const bf16* vb = v + (size_t)b * T_ * VDIM_ + h * DV_ + v0;
  const float* gb = g + (size_t)b * T_ * H_ + h;
  const float* bb = beta + (size_t)b * T_ * H_ + h;
  bf16* ob = o + (size_t)b * T_ * VDIM_ + h * DV_ + v0;

  for (int t = 0; t < T_; t++) {
    ks[tid] = bf2f(kb[(size_t)t * KDIM_ + tid]);
    qs[tid] = bf2f(qb[(size_t)t * KDIM_ + tid]);
    float vt = bf2f(vb[(size_t)t * VDIM_ + vl]);
    float gt = gb[(size_t)t * H_];
    float bt = bb[(size_t)t * H_];
    __syncthreads();
    float eg = expf(gt);

    float kr[32];
    float mem_p = 0.f;
#pragma unroll
    for (int j = 0; j < 32; j++) { kr[j] = ks[kg * 32 + j]; mem_p += kr[j] * S[j]; }
    mem_p += __shfl_xor(mem_p, 32, 64);
    if (lane < 32) red[w * 32 + lane] = mem_p;
    __syncthreads();
    if (tid < 32) {
      float m = red[tid] + red[32 + tid] + red[64 + tid] + red[96 + tid];
      dm[tid] = (vt - eg * m) * bt;
    }
    __syncthreads();
    float d = dm[vl];
    float o_p = 0.f;
#pragma unroll
    for (int j = 0; j < 32; j++) {
      S[j] = S[j] * eg + kr[j] * d;
      o_p += qs[kg * 32 + j] * S[j];
    }
    o_p += __shfl_xor(o_p, 32, 64);
    if (lane < 32) red2[w * 32 + lane] = o_p;
    __syncthreads();
    if (tid < 32)
      ob[(size_t)t * VDIM_ + tid] = f2bf(red2[tid] + red2[32 + tid] + red2[64 + tid] + red2[96 + tid]);
  }
}

// ---------------- gated RMSNorm (in place, bf16) ----------------

__global__ __launch_bounds__(256) void gated_rms_kernel(bf16* __restrict__ o,
                                                        const bf16* __restrict__ gate,
                                                        const float* __restrict__ onw) {
  __shared__ float red[4];
  int blk = blockIdx.x;
  int h = blk & 3;
  int bt = blk >> 2;
  size_t base = (size_t)bt * VDIM_ + h * DV_;
  int tid = threadIdx.x;
  float o1 = bf2f(o[base + tid]), o2 = bf2f(o[base + tid + 256]);
  float ss = block_sum256(o1 * o1 + o2 * o2, red);
  float s = rsqrtf(ss * (1.f / DV_) + 1e-5f);
  float g1 = bf2f(gate[base + tid]), g2 = bf2f(gate[base + tid + 256]);
  o[base + tid]       = f2bf(o1 * s * onw[tid] * siluf_(g1));
  o[base + tid + 256] = f2bf(o2 * s * onw[tid + 256] * siluf_(g2));
}

// ---------------- launch ----------------

extern "C" void kernel_launch(void* const* d_in, const int* in_sizes, int n_in,
                              void* d_out, int out_size, void* d_ws, size_t ws_size,
                              hipStream_t stream) {
  const float* x        = (const float*)d_in[0];
  const float* Wq       = (const float*)d_in[1];
  const float* Wk       = (const float*)d_in[2];
  const float* Wv       = (const float*)d_in[3];
  const float* Wa       = (const float*)d_in[4];
  const float* Wb       = (const float*)d_in[5];
  const float* Wg       = (const float*)d_in[6];
  const float* conv_q_w = (const float*)d_in[7];
  const float* conv_k_w = (const float*)d_in[8];
  const float* conv_v_w = (const float*)d_in[9];
  const float* A_log    = (const float*)d_in[10];
  const float* dt_bias  = (const float*)d_in[11];
  const float* o_norm_w = (const float*)d_in[12];
  const float* Wo       = (const float*)d_in[13];
  const float* ln1_w    = (const float*)d_in[14];
  const float* ln1_b    = (const float*)d_in[15];
  const float* ln2_w    = (const float*)d_in[16];
  const float* ln2_b    = (const float*)d_in[17];
  const float* ffn_w1   = (const float*)d_in[18];
  const float* ffn_b1   = (const float*)d_in[19];
  const float* ffn_w2   = (const float*)d_in[20];
  const float* ffn_b2   = (const float*)d_in[21];

  size_t required = (size_t)218 << 20;
  if (ws_size < required) {
    sentinel_kernel<<<(out_size + 255) / 256, 256, 0, stream>>>((float*)d_out, out_size);
    return;
  }

  char* base = (char*)d_ws;
  float* pre    = (float*)(base);                        // 64MB scratch (proj outs)
  bf16*  normed = (bf16*)(base + ((size_t)64  << 20));   // 16MB
  bf16*  q16    = (bf16*)(base + ((size_t)80  << 20));   // 16MB
  bf16*  k16    = (bf16*)(base + ((size_t)96  << 20));   // 16MB
  bf16*  v16    = (bf16*)(base + ((size_t)112 << 20));   // 32MB
  bf16*  g16    = (bf16*)(base + ((size_t)144 << 20));   // 32MB
  bf16*  o16    = (bf16*)(base + ((size_t)176 << 20));   // 32MB
  bf16*  wslot  = (bf16*)(base + ((size_t)208 << 20));   // 8MB JIT weight slot
  float* gvec   = (float*)(base + ((size_t)216 << 20));  // 128KB
  float* bvec   = gvec + (size_t)BT_ * H_;
  // reuses (serial on stream):
  float* x2     = (float*)(base);                        // 32MB, pre dead
  bf16*  hb16   = (bf16*)(base + ((size_t)64  << 20));   // normed dead
  bf16*  ffn1   = (bf16*)(base + ((size_t)80  << 20));   // 64MB, q/k/v dead

  // 1) LN1 -> bf16
  ln_kernel<<<BT_, 256, 0, stream>>>(x, ln1_w, ln1_b, normed);

  // 2) q/k/v/gate projections (bf16 MFMA; weights JIT-transposed into wslot) + convs
  convT_kernel<<<dim3(KDIM_ / 32, D_ / 32), 256, 0, stream>>>(Wq, wslot, D_, KDIM_);
  gemm_mfma<float><<<dim3(KDIM_ / 128, BT_ / 128), 256, 0, stream>>>(normed, wslot, nullptr, nullptr, pre, KDIM_, D_, 0);
  conv_qk_kernel<<<BT_ * H_, 256, 0, stream>>>(pre, conv_q_w, q16, 0.0625f);

  convT_kernel<<<dim3(KDIM_ / 32, D_ / 32), 256, 0, stream>>>(Wk, wslot, D_, KDIM_);
  gemm_mfma<float><<<dim3(KDIM_ / 128, BT_ / 128), 256, 0, stream>>>(normed, wslot, nullptr, nullptr, pre, KDIM_, D_, 0);
  conv_qk_kernel<<<BT_ * H_, 256, 0, stream>>>(pre, conv_k_w, k16, 1.0f);

  convT_kernel<<<dim3(VDIM_ / 32, D_ / 32), 256, 0, stream>>>(Wv, wslot, D_, VDIM_);
  gemm_mfma<float><<<dim3(VDIM_ / 128, BT_ / 128), 256, 0, stream>>>(normed, wslot, nullptr, nullptr, pre, VDIM_, D_, 0);
  conv_v_kernel<<<(BT_ * VDIM_) / 256, 256, 0, stream>>>(pre, conv_v_w, v16);

  convT_kernel<<<dim3(VDIM_ / 32, D_ / 32), 256, 0, stream>>>(Wg, wslot, D_, VDIM_);
  gemm_mfma<bf16><<<dim3(VDIM_ / 128, BT_ / 128), 256, 0, stream>>>(normed, wslot, nullptr, nullptr, g16, VDIM_, D_, 0);

  ab_kernel<<<BT_, 256, 0, stream>>>(normed, Wa, Wb, A_log, dt_bias, gvec, bvec);

  // 3) gated delta rule
  delta_kernel<<<B_ * H_ * (DV_ / 32), 256, 0, stream>>>(q16, k16, v16, gvec, bvec, o16);

  // 4) gated RMSNorm (in place)
  gated_rms_kernel<<<BT_ * H_, 256, 0, stream>>>(o16, g16, o_norm_w);

  // 5) x2 = x + o @ Wo
  convT_kernel<<<dim3(D_ / 32, VDIM_ / 32), 256, 0, stream>>>(Wo, wslot, VDIM_, D_);
  gemm_mfma<float><<<dim3(D_ / 128, BT_ / 128), 256, 0, stream>>>(o16, wslot, nullptr, x, x2, D_, VDIM_, 4);

  // 6) LN2 -> bf16
  ln_kernel<<<BT_, 256, 0, stream>>>(x2, ln2_w, ln2_b, hb16);

  // 7) FFN
  convT_kernel<<<dim3(FFN_ / 32, D_ / 32), 256, 0, stream>>>(ffn_w1, wslot, D_, FFN_);
  gemm_mfma<bf16><<<dim3(FFN_ / 128, BT_ / 128), 256, 0, stream>>>(hb16, wslot, ffn_b1, nullptr, ffn1, FFN_, D_, 1 | 2);
  convT_kernel<<<dim3(D_ / 32, FFN_ / 32), 256, 0, stream>>>(ffn_w2, wslot, FFN_, D_);
  gemm_mfma<float><<<dim3(D_ / 128, BT_ / 128), 256, 0, stream>>>(ffn1, wslot, ffn_b2, x2, (float*)d_out, D_, FFN_, 1 | 4);
}

// Round 4
// 2921.868 us; speedup vs baseline: 2.4303x; 1.0781x over previous
//
#include <hip/hip_runtime.h>
#include <math.h>

#define B_    4
#define T_    2048
#define D_    1024
#define H_    4
#define DK_   256
#define DV_   512
#define KDIM_ 1024
#define VDIM_ 2048
#define FFN_  4096
#define BT_   8192   // B_*T_

typedef unsigned short bf16;
typedef __attribute__((ext_vector_type(8))) short short8;   // MFMA A/B frag (8 bf16)
typedef __attribute__((ext_vector_type(4))) float f32x4;    // MFMA C/D frag

// ---------------- helpers ----------------

__device__ __forceinline__ float sigmoidf_(float x) { return 1.f / (1.f + expf(-x)); }
__device__ __forceinline__ float siluf_(float x)    { return x / (1.f + expf(-x)); }
__device__ __forceinline__ float geluf_(float x)    { return 0.5f * x * (1.f + erff(x * 0.70710678118654752f)); }

__device__ __forceinline__ float bf2f(bf16 u) {
  union { unsigned int i; float f; } c; c.i = (unsigned int)u << 16; return c.f;
}
__device__ __forceinline__ bf16 f2bf(float f) {
  union { unsigned int i; float f; } c; c.f = f;
  unsigned int r = c.i + 0x7fffu + ((c.i >> 16) & 1u);   // RNE
  return (bf16)(r >> 16);
}

// async global->LDS, 16B per lane; lds dest = uniform base + lane*16
__device__ __forceinline__ void gload16(const bf16* g, bf16* l) {
  __builtin_amdgcn_global_load_lds((__attribute__((address_space(1))) const void*)g,
                                   (__attribute__((address_space(3))) void*)l, 16, 0, 0);
}

__device__ __forceinline__ void storeC(float* p, float v) { *p = v; }
__device__ __forceinline__ void storeC(bf16* p, float v)  { *p = f2bf(v); }

// block of exactly 256 threads; returns same sum to all threads
__device__ __forceinline__ float block_sum256(float v, float* red) {
#pragma unroll
  for (int off = 32; off; off >>= 1) v += __shfl_xor(v, off, 64);
  __syncthreads();
  if ((threadIdx.x & 63) == 0) red[threadIdx.x >> 6] = v;
  __syncthreads();
  return red[0] + red[1] + red[2] + red[3];
}

// ---------------- diagnostic sentinel (ws too small) ----------------

__global__ __launch_bounds__(256) void sentinel_kernel(float* out, int n) {
  int i = blockIdx.x * 256 + threadIdx.x;
  if (i < n) out[i] = 12345.0f;
}

// ---------------- LayerNorm (one row per block) -> bf16 out ----------------

__global__ __launch_bounds__(256) void ln_kernel(const float* __restrict__ x,
                                                 const float* __restrict__ w,
                                                 const float* __restrict__ b,
                                                 bf16* __restrict__ y) {
  __shared__ float red[4];
  int row = blockIdx.x;
  const float* xr = x + (size_t)row * D_;
  float xv[4];
  float s = 0.f;
#pragma unroll
  for (int i = 0; i < 4; i++) { xv[i] = xr[threadIdx.x + 256 * i]; s += xv[i]; }
  float mean = block_sum256(s, red) * (1.f / D_);
  float s2 = 0.f;
#pragma unroll
  for (int i = 0; i < 4; i++) { float d = xv[i] - mean; s2 += d * d; }
  float var = block_sum256(s2, red) * (1.f / D_);
  float inv = rsqrtf(var + 1e-5f);
  bf16* yr = y + (size_t)row * D_;
#pragma unroll
  for (int i = 0; i < 4; i++) {
    int c = threadIdx.x + 256 * i;
    yr[c] = f2bf((xv[i] - mean) * inv * w[c] + b[c]);
  }
}

// ---------------- weight convert+transpose: fp32 [K][N] -> bf16 [N][K] ----------------

__global__ __launch_bounds__(256) void convT_kernel(const float* __restrict__ src,
                                                    bf16* __restrict__ dst,
                                                    int K, int N) {
  __shared__ float t[32][33];
  int n0 = blockIdx.x * 32, k0 = blockIdx.y * 32;
  int tx = threadIdx.x & 31, ty = threadIdx.x >> 5;   // ty 0..7
#pragma unroll
  for (int i = 0; i < 4; i++)
    t[ty + i * 8][tx] = src[(size_t)(k0 + ty + i * 8) * N + n0 + tx];
  __syncthreads();
#pragma unroll
  for (int i = 0; i < 4; i++)
    dst[(size_t)(n0 + ty + i * 8) * K + k0 + tx] = f2bf(t[tx][ty + i * 8]);
}

// ---------------- bf16 MFMA GEMM ----------------
// A [M][K] bf16 row-major, Bt [N][K] bf16 row-major (transposed weights).
// 128x128 block tile, BK=32, 4 waves (2x2), each wave 4x4 16x16 tiles.
// flags: 1=add bias[col] (fp32), 2=gelu, 4=add res[row*N+col] (fp32)

template <typename TC>
__global__ __launch_bounds__(256) void gemm_mfma(const bf16* __restrict__ A,
                                                 const bf16* __restrict__ Bt,
                                                 const float* __restrict__ bias,
                                                 const float* __restrict__ res,
                                                 TC* __restrict__ C,
                                                 int N, int K, int flags) {
  __shared__ __align__(16) bf16 As[128 * 32];   // [m][k] 8KB
  __shared__ __align__(16) bf16 Bs[128 * 32];   // [n][k] 8KB
  int tid = threadIdx.x;
  int wave = tid >> 6, lane = tid & 63;
  int bm = blockIdx.y * 128, bn = blockIdx.x * 128;
  int wm = (wave >> 1) * 64, wn = (wave & 1) * 64;
  int lm = lane & 15;        // m (A) / n (B) / col (D)
  int quad = lane >> 4;      // 0..3

  f32x4 acc[4][4];
#pragma unroll
  for (int i = 0; i < 4; i++)
#pragma unroll
    for (int j = 0; j < 4; j++) acc[i][j] = (f32x4){0.f, 0.f, 0.f, 0.f};

  int srow = wave * 32 + (lane >> 2);
  int scol = (lane & 3) * 8;
  const bf16* ag = A  + (size_t)(bm + srow) * K + scol;
  const bf16* bg = Bt + (size_t)(bn + srow) * K + scol;
  bf16* al = As + wave * 32 * 32;
  bf16* bl = Bs + wave * 32 * 32;
  const size_t gstep = (size_t)16 * K;

  for (int k0 = 0; k0 < K; k0 += 32) {
    gload16(ag + k0,         al);
    gload16(ag + k0 + gstep, al + 16 * 32);
    gload16(bg + k0,         bl);
    gload16(bg + k0 + gstep, bl + 16 * 32);
    __syncthreads();

    short8 af[4], bf[4];
#pragma unroll
    for (int i = 0; i < 4; i++)
      af[i] = *(const short8*)&As[(wm + i * 16 + lm) * 32 + quad * 8];
#pragma unroll
    for (int j = 0; j < 4; j++)
      bf[j] = *(const short8*)&Bs[(wn + j * 16 + lm) * 32 + quad * 8];
#pragma unroll
    for (int i = 0; i < 4; i++)
#pragma unroll
      for (int j = 0; j < 4; j++)
        acc[i][j] = __builtin_amdgcn_mfma_f32_16x16x32_bf16(af[i], bf[j], acc[i][j], 0, 0, 0);
    __syncthreads();
  }

#pragma unroll
  for (int i = 0; i < 4; i++) {
    int row0 = bm + wm + i * 16 + quad * 4;
#pragma unroll
    for (int j = 0; j < 4; j++) {
      int col = bn + wn + j * 16 + lm;
      float badd = (flags & 1) ? bias[col] : 0.f;
#pragma unroll
      for (int r = 0; r < 4; r++) {
        float v = acc[i][j][r] + badd;
        if (flags & 2) v = geluf_(v);
        if (flags & 4) v += res[(size_t)(row0 + r) * N + col];
        storeC(&C[(size_t)(row0 + r) * N + col], v);
      }
    }
  }
}

// ---------------- fused Wa/Wb projections -> g, beta ----------------

__global__ __launch_bounds__(256) void ab_kernel(const bf16* __restrict__ normed,
                                                 const float* __restrict__ Wa,
                                                 const float* __restrict__ Wb,
                                                 const float* __restrict__ A_log,
                                                 const float* __restrict__ dt_bias,
                                                 float* __restrict__ g,
                                                 float* __restrict__ beta) {
  __shared__ float red[4];
  int row = blockIdx.x;
  const bf16* xr = normed + (size_t)row * D_;
  float aacc[4] = {}, bacc[4] = {};
#pragma unroll
  for (int i = 0; i < 4; i++) {
    int d = threadIdx.x + 256 * i;
    float xv = bf2f(xr[d]);
    float4 wa = *(const float4*)&Wa[d * 4];
    float4 wb = *(const float4*)&Wb[d * 4];
    aacc[0] += xv * wa.x; aacc[1] += xv * wa.y; aacc[2] += xv * wa.z; aacc[3] += xv * wa.w;
    bacc[0] += xv * wb.x; bacc[1] += xv * wb.y; bacc[2] += xv * wb.z; bacc[3] += xv * wb.w;
  }
  float sa[4], sb[4];
#pragma unroll
  for (int h = 0; h < 4; h++) {
    sa[h] = block_sum256(aacc[h], red);
    sb[h] = block_sum256(bacc[h], red);
  }
  if (threadIdx.x < 4) {
    int h = threadIdx.x;
    float xa = sa[h] + dt_bias[h];
    float sp = (xa > 20.f) ? xa : log1pf(expf(xa));
    g[row * 4 + h] = -expf(A_log[h]) * sp;
    beta[row * 4 + h] = sigmoidf_(sb[h]);
  }
}

// ---------------- causal conv(4) + SiLU + per-head L2 norm (q/k) ----------------

__global__ __launch_bounds__(256) void conv_qk_kernel(const float* __restrict__ pre,
                                                      const float* __restrict__ convw,
                                                      bf16* __restrict__ out,
                                                      float scale) {
  __shared__ float red[4];
  int blk = blockIdx.x;
  int h = blk & 3;
  int bt = blk >> 2;
  int t = bt & (T_ - 1);
  int c = h * DK_ + threadIdx.x;
  float y = 0.f;
#pragma unroll
  for (int i = 0; i < 4; i++) {
    int tt = t + i - 3;
    if (tt >= 0) y += pre[(size_t)(bt + i - 3) * KDIM_ + c] * convw[c * 4 + i];
  }
  y = siluf_(y);
  float ss = block_sum256(y * y, red);
  y *= rsqrtf(ss + 1e-6f) * scale;
  out[(size_t)bt * KDIM_ + c] = f2bf(y);
}

__global__ __launch_bounds__(256) void conv_v_kernel(const float* __restrict__ pre,
                                                     const float* __restrict__ convw,
                                                     bf16* __restrict__ out) {
  int idx = blockIdx.x * 256 + threadIdx.x;
  int c = idx & (VDIM_ - 1);
  int bt = idx >> 11;
  int t = bt & (T_ - 1);
  float y = 0.f;
#pragma unroll
  for (int i = 0; i < 4; i++) {
    int tt = t + i - 3;
    if (tt >= 0) y += pre[(size_t)(bt + i - 3) * VDIM_ + c] * convw[c * 4 + i];
  }
  out[idx] = f2bf(siluf_(y));
}

// ---------------- gated delta rule recurrence (wave-per-block, R4) ----------------
// grid = B*H*64 = 1024 single-wave blocks; each block owns 8 v-cols.
// lane = kg*8 + vl (kg 0..7 = k-row group, vl 0..7 = v-col). Thread owns
// S[kg*32 .. kg*32+31][v0+vl] in 32 fp32 regs. All reductions are 3x shfl_xor
// (over lane bits 3,4,5). LDS double-buffered k/q stage; t+1 globals
// prefetched into regs during step t compute.

__global__ __launch_bounds__(64) void delta_kernel(const bf16* __restrict__ q,
                                                   const bf16* __restrict__ k,
                                                   const bf16* __restrict__ v,
                                                   const float* __restrict__ g,
                                                   const float* __restrict__ beta,
                                                   bf16* __restrict__ o) {
  __shared__ float ks[2][256], qs[2][256];
  int blk = blockIdx.x;
  int chunk = blk & 63;        // 64 chunks of 8 cols
  int bh = blk >> 6;
  int b = bh >> 2, h = bh & 3;
  int lane = threadIdx.x;
  int kg = lane >> 3, vl = lane & 7;
  int v0 = chunk * 8;

  float S[32];
#pragma unroll
  for (int j = 0; j < 32; j++) S[j] = 0.f;

  const bf16* kb = k + (size_t)b * T_ * KDIM_ + h * DK_ + lane * 4;
  const bf16* qb = q + (size_t)b * T_ * KDIM_ + h * DK_ + lane * 4;
  const bf16* vb = v + (size_t)b * T_ * VDIM_ + h * DV_ + v0 + vl;
  const float* gb = g + (size_t)b * T_ * H_ + h;
  const float* bb = beta + (size_t)b * T_ * H_ + h;
  bf16* ob = o + (size_t)b * T_ * VDIM_ + h * DV_ + v0 + vl;

  // prefetch t=0
  ushort4 kv = *(const ushort4*)kb;
  ushort4 qv = *(const ushort4*)qb;
  bf16 vvx = *vb;
  float gtn = *gb, btn = *bb;

  for (int t = 0; t < T_; t++) {
    float* ksb = ks[t & 1];
    float* qsb = qs[t & 1];
    float4 kf = make_float4(bf2f(kv.x), bf2f(kv.y), bf2f(kv.z), bf2f(kv.w));
    float4 qf = make_float4(bf2f(qv.x), bf2f(qv.y), bf2f(qv.z), bf2f(qv.w));
    *(float4*)&ksb[lane * 4] = kf;
    *(float4*)&qsb[lane * 4] = qf;
    float vt = bf2f(vvx), gcur = gtn, bcur = btn;
    if (t + 1 < T_) {                       // prefetch t+1 during compute
      kv  = *(const ushort4*)(kb + (size_t)(t + 1) * KDIM_);
      qv  = *(const ushort4*)(qb + (size_t)(t + 1) * KDIM_);
      vvx = vb[(size_t)(t + 1) * VDIM_];
      gtn = gb[(size_t)(t + 1) * H_];
      btn = bb[(size_t)(t + 1) * H_];
    }
    __syncthreads();                        // single-wave barrier: LDS writes visible

    float eg = expf(gcur);
    const float* kk = &ksb[kg * 32];
    const float* qq = &qsb[kg * 32];
    float kr[32];
    float m0 = 0.f, m1 = 0.f, m2 = 0.f, m3 = 0.f;
#pragma unroll
    for (int j = 0; j < 32; j += 4) {
      kr[j] = kk[j]; kr[j + 1] = kk[j + 1]; kr[j + 2] = kk[j + 2]; kr[j + 3] = kk[j + 3];
      m0 += kr[j] * S[j]; m1 += kr[j + 1] * S[j + 1];
      m2 += kr[j + 2] * S[j + 2]; m3 += kr[j + 3] * S[j + 3];
    }
    float mem = (m0 + m1) + (m2 + m3);
    mem += __shfl_xor(mem, 8, 64);
    mem += __shfl_xor(mem, 16, 64);
    mem += __shfl_xor(mem, 32, 64);
    float d = (vt - eg * mem) * bcur;

    float o0 = 0.f, o1 = 0.f, o2 = 0.f, o3 = 0.f;
#pragma unroll
    for (int j = 0; j < 32; j += 4) {
      S[j]     = S[j]     * eg + kr[j]     * d;  o0 += qq[j]     * S[j];
      S[j + 1] = S[j + 1] * eg + kr[j + 1] * d;  o1 += qq[j + 1] * S[j + 1];
      S[j + 2] = S[j + 2] * eg + kr[j + 2] * d;  o2 += qq[j + 2] * S[j + 2];
      S[j + 3] = S[j + 3] * eg + kr[j + 3] * d;  o3 += qq[j + 3] * S[j + 3];
    }
    float op = (o0 + o1) + (o2 + o3);
    op += __shfl_xor(op, 8, 64);
    op += __shfl_xor(op, 16, 64);
    op += __shfl_xor(op, 32, 64);
    if (kg == 0) ob[(size_t)t * VDIM_] = f2bf(op);
  }
}

// ---------------- gated RMSNorm (in place, bf16) ----------------

__global__ __launch_bounds__(256) void gated_rms_kernel(bf16* __restrict__ o,
                                                        const bf16* __restrict__ gate,
                                                        const float* __restrict__ onw) {
  __shared__ float red[4];
  int blk = blockIdx.x;
  int h = blk & 3;
  int bt = blk >> 2;
  size_t base = (size_t)bt * VDIM_ + h * DV_;
  int tid = threadIdx.x;
  float o1 = bf2f(o[base + tid]), o2 = bf2f(o[base + tid + 256]);
  float ss = block_sum256(o1 * o1 + o2 * o2, red);
  float s = rsqrtf(ss * (1.f / DV_) + 1e-5f);
  float g1 = bf2f(gate[base + tid]), g2 = bf2f(gate[base + tid + 256]);
  o[base + tid]       = f2bf(o1 * s * onw[tid] * siluf_(g1));
  o[base + tid + 256] = f2bf(o2 * s * onw[tid + 256] * siluf_(g2));
}

// ---------------- launch ----------------

extern "C" void kernel_launch(void* const* d_in, const int* in_sizes, int n_in,
                              void* d_out, int out_size, void* d_ws, size_t ws_size,
                              hipStream_t stream) {
  const float* x        = (const float*)d_in[0];
  const float* Wq       = (const float*)d_in[1];
  const float* Wk       = (const float*)d_in[2];
  const float* Wv       = (const float*)d_in[3];
  const float* Wa       = (const float*)d_in[4];
  const float* Wb       = (const float*)d_in[5];
  const float* Wg       = (const float*)d_in[6];
  const float* conv_q_w = (const float*)d_in[7];
  const float* conv_k_w = (const float*)d_in[8];
  const float* conv_v_w = (const float*)d_in[9];
  const float* A_log    = (const float*)d_in[10];
  const float* dt_bias  = (const float*)d_in[11];
  const float* o_norm_w = (const float*)d_in[12];
  const float* Wo       = (const float*)d_in[13];
  const float* ln1_w    = (const float*)d_in[14];
  const float* ln1_b    = (const float*)d_in[15];
  const float* ln2_w    = (const float*)d_in[16];
  const float* ln2_b    = (const float*)d_in[17];
  const float* ffn_w1   = (const float*)d_in[18];
  const float* ffn_b1   = (const float*)d_in[19];
  const float* ffn_w2   = (const float*)d_in[20];
  const float* ffn_b2   = (const float*)d_in[21];

  size_t required = (size_t)218 << 20;
  if (ws_size < required) {
    sentinel_kernel<<<(out_size + 255) / 256, 256, 0, stream>>>((float*)d_out, out_size);
    return;
  }

  char* base = (char*)d_ws;
  float* pre    = (float*)(base);                        // 64MB scratch (proj outs)
  bf16*  normed = (bf16*)(base + ((size_t)64  << 20));   // 16MB
  bf16*  q16    = (bf16*)(base + ((size_t)80  << 20));   // 16MB
  bf16*  k16    = (bf16*)(base + ((size_t)96  << 20));   // 16MB
  bf16*  v16    = (bf16*)(base + ((size_t)112 << 20));   // 32MB
  bf16*  g16    = (bf16*)(base + ((size_t)144 << 20));   // 32MB
  bf16*  o16    = (bf16*)(base + ((size_t)176 << 20));   // 32MB
  bf16*  wslot  = (bf16*)(base + ((size_t)208 << 20));   // 8MB JIT weight slot
  float* gvec   = (float*)(base + ((size_t)216 << 20));  // 128KB
  float* bvec   = gvec + (size_t)BT_ * H_;
  // reuses (serial on stream):
  float* x2     = (float*)(base);                        // 32MB, pre dead
  bf16*  hb16   = (bf16*)(base + ((size_t)64  << 20));   // normed dead
  bf16*  ffn1   = (bf16*)(base + ((size_t)80  << 20));   // 64MB, q/k/v dead

  // 1) LN1 -> bf16
  ln_kernel<<<BT_, 256, 0, stream>>>(x, ln1_w, ln1_b, normed);

  // 2) q/k/v/gate projections (bf16 MFMA; weights JIT-transposed into wslot) + convs
  convT_kernel<<<dim3(KDIM_ / 32, D_ / 32), 256, 0, stream>>>(Wq, wslot, D_, KDIM_);
  gemm_mfma<float><<<dim3(KDIM_ / 128, BT_ / 128), 256, 0, stream>>>(normed, wslot, nullptr, nullptr, pre, KDIM_, D_, 0);
  conv_qk_kernel<<<BT_ * H_, 256, 0, stream>>>(pre, conv_q_w, q16, 0.0625f);

  convT_kernel<<<dim3(KDIM_ / 32, D_ / 32), 256, 0, stream>>>(Wk, wslot, D_, KDIM_);
  gemm_mfma<float><<<dim3(KDIM_ / 128, BT_ / 128), 256, 0, stream>>>(normed, wslot, nullptr, nullptr, pre, KDIM_, D_, 0);
  conv_qk_kernel<<<BT_ * H_, 256, 0, stream>>>(pre, conv_k_w, k16, 1.0f);

  convT_kernel<<<dim3(VDIM_ / 32, D_ / 32), 256, 0, stream>>>(Wv, wslot, D_, VDIM_);
  gemm_mfma<float><<<dim3(VDIM_ / 128, BT_ / 128), 256, 0, stream>>>(normed, wslot, nullptr, nullptr, pre, VDIM_, D_, 0);
  conv_v_kernel<<<(BT_ * VDIM_) / 256, 256, 0, stream>>>(pre, conv_v_w, v16);

  convT_kernel<<<dim3(VDIM_ / 32, D_ / 32), 256, 0, stream>>>(Wg, wslot, D_, VDIM_);
  gemm_mfma<bf16><<<dim3(VDIM_ / 128, BT_ / 128), 256, 0, stream>>>(normed, wslot, nullptr, nullptr, g16, VDIM_, D_, 0);

  ab_kernel<<<BT_, 256, 0, stream>>>(normed, Wa, Wb, A_log, dt_bias, gvec, bvec);

  // 3) gated delta rule (wave-per-block)
  delta_kernel<<<B_ * H_ * 64, 64, 0, stream>>>(q16, k16, v16, gvec, bvec, o16);

  // 4) gated RMSNorm (in place)
  gated_rms_kernel<<<BT_ * H_, 256, 0, stream>>>(o16, g16, o_norm_w);

  // 5) x2 = x + o @ Wo
  convT_kernel<<<dim3(D_ / 32, VDIM_ / 32), 256, 0, stream>>>(Wo, wslot, VDIM_, D_);
  gemm_mfma<float><<<dim3(D_ / 128, BT_ / 128), 256, 0, stream>>>(o16, wslot, nullptr, x, x2, D_, VDIM_, 4);

  // 6) LN2 -> bf16
  ln_kernel<<<BT_, 256, 0, stream>>>(x2, ln2_w, ln2_b, hb16);

  // 7) FFN
  convT_kernel<<<dim3(FFN_ / 32, D_ / 32), 256, 0, stream>>>(ffn_w1, wslot, D_, FFN_);
  gemm_mfma<bf16><<<dim3(FFN_ / 128, BT_ / 128), 256, 0, stream>>>(hb16, wslot, ffn_b1, nullptr, ffn1, FFN_, D_, 1 | 2);
  convT_kernel<<<dim3(D_ / 32, FFN_ / 32), 256, 0, stream>>>(ffn_w2, wslot, FFN_, D_);
  gemm_mfma<float><<<dim3(D_ / 128, BT_ / 128), 256, 0, stream>>>(ffn1, wslot, ffn_b2, x2, (float*)d_out, D_, FFN_, 1 | 4);
}

// Round 5
// 1765.973 us; speedup vs baseline: 4.0210x; 1.6545x over previous
//
#include <hip/hip_runtime.h>
#include <math.h>

#define B_    4
#define T_    2048
#define D_    1024
#define H_    4
#define DK_   256
#define DV_   512
#define KDIM_ 1024
#define VDIM_ 2048
#define FFN_  4096
#define BT_   8192   // B_*T_

typedef unsigned short bf16;
typedef __attribute__((ext_vector_type(8))) short short8;   // MFMA A/B frag (8 bf16)
typedef __attribute__((ext_vector_type(4))) short short4v;  // 4 bf16
typedef __attribute__((ext_vector_type(4))) float f32x4;    // MFMA C/D frag

// ---------------- helpers ----------------

__device__ __forceinline__ float sigmoidf_(float x) { return 1.f / (1.f + expf(-x)); }
__device__ __forceinline__ float siluf_(float x)    { return x / (1.f + expf(-x)); }
__device__ __forceinline__ float geluf_(float x)    { return 0.5f * x * (1.f + erff(x * 0.70710678118654752f)); }

__device__ __forceinline__ float bf2f(bf16 u) {
  union { unsigned int i; float f; } c; c.i = (unsigned int)u << 16; return c.f;
}
__device__ __forceinline__ bf16 f2bf(float f) {
  union { unsigned int i; float f; } c; c.f = f;
  unsigned int r = c.i + 0x7fffu + ((c.i >> 16) & 1u);   // RNE
  return (bf16)(r >> 16);
}

// async global->LDS, 16B per lane
__device__ __forceinline__ void gload16(const bf16* g, bf16* l) {
  __builtin_amdgcn_global_load_lds((__attribute__((address_space(1))) const void*)g,
                                   (__attribute__((address_space(3))) void*)l, 16, 0, 0);
}

__device__ __forceinline__ void storeC(float* p, float v) { *p = v; }
__device__ __forceinline__ void storeC(bf16* p, float v)  { *p = f2bf(v); }

// load 8 bf16 from an 8B-aligned (not 16B) LDS address as two b64s
__device__ __forceinline__ short8 ld76(const bf16* p) {
  union { short8 v; short4v h[2]; } u;
  u.h[0] = *(const short4v*)p;
  u.h[1] = *(const short4v*)(p + 4);
  return u.v;
}
// pack f32x4 -> 4 bf16, 8B store
__device__ __forceinline__ void st4bf(bf16* p, f32x4 v) {
  short4v o;
  o[0] = (short)f2bf(v[0]); o[1] = (short)f2bf(v[1]);
  o[2] = (short)f2bf(v[2]); o[3] = (short)f2bf(v[3]);
  *(short4v*)p = o;
}

__device__ __forceinline__ float block_sum256(float v, float* red) {
#pragma unroll
  for (int off = 32; off; off >>= 1) v += __shfl_xor(v, off, 64);
  __syncthreads();
  if ((threadIdx.x & 63) == 0) red[threadIdx.x >> 6] = v;
  __syncthreads();
  return red[0] + red[1] + red[2] + red[3];
}

// ---------------- diagnostic sentinel (ws too small) ----------------

__global__ __launch_bounds__(256) void sentinel_kernel(float* out, int n) {
  int i = blockIdx.x * 256 + threadIdx.x;
  if (i < n) out[i] = 12345.0f;
}

// ---------------- LayerNorm -> bf16 ----------------

__global__ __launch_bounds__(256) void ln_kernel(const float* __restrict__ x,
                                                 const float* __restrict__ w,
                                                 const float* __restrict__ b,
                                                 bf16* __restrict__ y) {
  __shared__ float red[4];
  int row = blockIdx.x;
  const float* xr = x + (size_t)row * D_;
  float xv[4];
  float s = 0.f;
#pragma unroll
  for (int i = 0; i < 4; i++) { xv[i] = xr[threadIdx.x + 256 * i]; s += xv[i]; }
  float mean = block_sum256(s, red) * (1.f / D_);
  float s2 = 0.f;
#pragma unroll
  for (int i = 0; i < 4; i++) { float d = xv[i] - mean; s2 += d * d; }
  float var = block_sum256(s2, red) * (1.f / D_);
  float inv = rsqrtf(var + 1e-5f);
  bf16* yr = y + (size_t)row * D_;
#pragma unroll
  for (int i = 0; i < 4; i++) {
    int c = threadIdx.x + 256 * i;
    yr[c] = f2bf((xv[i] - mean) * inv * w[c] + b[c]);
  }
}

// ---------------- weight convert+transpose: fp32 [K][N] -> bf16 [N][K] ----------------

__global__ __launch_bounds__(256) void convT_kernel(const float* __restrict__ src,
                                                    bf16* __restrict__ dst,
                                                    int K, int N) {
  __shared__ float t[32][33];
  int n0 = blockIdx.x * 32, k0 = blockIdx.y * 32;
  int tx = threadIdx.x & 31, ty = threadIdx.x >> 5;
#pragma unroll
  for (int i = 0; i < 4; i++)
    t[ty + i * 8][tx] = src[(size_t)(k0 + ty + i * 8) * N + n0 + tx];
  __syncthreads();
#pragma unroll
  for (int i = 0; i < 4; i++)
    dst[(size_t)(n0 + ty + i * 8) * K + k0 + tx] = f2bf(t[tx][ty + i * 8]);
}

// ---------------- bf16 MFMA GEMM (unchanged from R3) ----------------

template <typename TC>
__global__ __launch_bounds__(256) void gemm_mfma(const bf16* __restrict__ A,
                                                 const bf16* __restrict__ Bt,
                                                 const float* __restrict__ bias,
                                                 const float* __restrict__ res,
                                                 TC* __restrict__ C,
                                                 int N, int K, int flags) {
  __shared__ __align__(16) bf16 As[128 * 32];
  __shared__ __align__(16) bf16 Bs[128 * 32];
  int tid = threadIdx.x;
  int wave = tid >> 6, lane = tid & 63;
  int bm = blockIdx.y * 128, bn = blockIdx.x * 128;
  int wm = (wave >> 1) * 64, wn = (wave & 1) * 64;
  int lm = lane & 15;
  int quad = lane >> 4;

  f32x4 acc[4][4];
#pragma unroll
  for (int i = 0; i < 4; i++)
#pragma unroll
    for (int j = 0; j < 4; j++) acc[i][j] = (f32x4){0.f, 0.f, 0.f, 0.f};

  int srow = wave * 32 + (lane >> 2);
  int scol = (lane & 3) * 8;
  const bf16* ag = A  + (size_t)(bm + srow) * K + scol;
  const bf16* bg = Bt + (size_t)(bn + srow) * K + scol;
  bf16* al = As + wave * 32 * 32;
  bf16* bl = Bs + wave * 32 * 32;
  const size_t gstep = (size_t)16 * K;

  for (int k0 = 0; k0 < K; k0 += 32) {
    gload16(ag + k0,         al);
    gload16(ag + k0 + gstep, al + 16 * 32);
    gload16(bg + k0,         bl);
    gload16(bg + k0 + gstep, bl + 16 * 32);
    __syncthreads();

    short8 af[4], bf[4];
#pragma unroll
    for (int i = 0; i < 4; i++)
      af[i] = *(const short8*)&As[(wm + i * 16 + lm) * 32 + quad * 8];
#pragma unroll
    for (int j = 0; j < 4; j++)
      bf[j] = *(const short8*)&Bs[(wn + j * 16 + lm) * 32 + quad * 8];
#pragma unroll
    for (int i = 0; i < 4; i++)
#pragma unroll
      for (int j = 0; j < 4; j++)
        acc[i][j] = __builtin_amdgcn_mfma_f32_16x16x32_bf16(af[i], bf[j], acc[i][j], 0, 0, 0);
    __syncthreads();
  }

#pragma unroll
  for (int i = 0; i < 4; i++) {
    int row0 = bm + wm + i * 16 + quad * 4;
#pragma unroll
    for (int j = 0; j < 4; j++) {
      int col = bn + wn + j * 16 + lm;
      float badd = (flags & 1) ? bias[col] : 0.f;
#pragma unroll
      for (int r = 0; r < 4; r++) {
        float v = acc[i][j][r] + badd;
        if (flags & 2) v = geluf_(v);
        if (flags & 4) v += res[(size_t)(row0 + r) * N + col];
        storeC(&C[(size_t)(row0 + r) * N + col], v);
      }
    }
  }
}

// ---------------- fused Wa/Wb projections -> g, beta ----------------

__global__ __launch_bounds__(256) void ab_kernel(const bf16* __restrict__ normed,
                                                 const float* __restrict__ Wa,
                                                 const float* __restrict__ Wb,
                                                 const float* __restrict__ A_log,
                                                 const float* __restrict__ dt_bias,
                                                 float* __restrict__ g,
                                                 float* __restrict__ beta) {
  __shared__ float red[4];
  int row = blockIdx.x;
  const bf16* xr = normed + (size_t)row * D_;
  float aacc[4] = {}, bacc[4] = {};
#pragma unroll
  for (int i = 0; i < 4; i++) {
    int d = threadIdx.x + 256 * i;
    float xv = bf2f(xr[d]);
    float4 wa = *(const float4*)&Wa[d * 4];
    float4 wb = *(const float4*)&Wb[d * 4];
    aacc[0] += xv * wa.x; aacc[1] += xv * wa.y; aacc[2] += xv * wa.z; aacc[3] += xv * wa.w;
    bacc[0] += xv * wb.x; bacc[1] += xv * wb.y; bacc[2] += xv * wb.z; bacc[3] += xv * wb.w;
  }
  float sa[4], sb[4];
#pragma unroll
  for (int h = 0; h < 4; h++) {
    sa[h] = block_sum256(aacc[h], red);
    sb[h] = block_sum256(bacc[h], red);
  }
  if (threadIdx.x < 4) {
    int h = threadIdx.x;
    float xa = sa[h] + dt_bias[h];
    float sp = (xa > 20.f) ? xa : log1pf(expf(xa));
    g[row * 4 + h] = -expf(A_log[h]) * sp;
    beta[row * 4 + h] = sigmoidf_(sb[h]);
  }
}

// ---------------- causal conv(4) + SiLU (+ L2 norm for q/k) ----------------

__global__ __launch_bounds__(256) void conv_qk_kernel(const float* __restrict__ pre,
                                                      const float* __restrict__ convw,
                                                      bf16* __restrict__ out,
                                                      float scale) {
  __shared__ float red[4];
  int blk = blockIdx.x;
  int h = blk & 3;
  int bt = blk >> 2;
  int t = bt & (T_ - 1);
  int c = h * DK_ + threadIdx.x;
  float y = 0.f;
#pragma unroll
  for (int i = 0; i < 4; i++) {
    int tt = t + i - 3;
    if (tt >= 0) y += pre[(size_t)(bt + i - 3) * KDIM_ + c] * convw[c * 4 + i];
  }
  y = siluf_(y);
  float ss = block_sum256(y * y, red);
  y *= rsqrtf(ss + 1e-6f) * scale;
  out[(size_t)bt * KDIM_ + c] = f2bf(y);
}

__global__ __launch_bounds__(256) void conv_v_kernel(const float* __restrict__ pre,
                                                     const float* __restrict__ convw,
                                                     bf16* __restrict__ out) {
  int idx = blockIdx.x * 256 + threadIdx.x;
  int c = idx & (VDIM_ - 1);
  int bt = idx >> 11;
  int t = bt & (T_ - 1);
  float y = 0.f;
#pragma unroll
  for (int i = 0; i < 4; i++) {
    int tt = t + i - 3;
    if (tt >= 0) y += pre[(size_t)(bt + i - 3) * VDIM_ + c] * convw[c * 4 + i];
  }
  out[idx] = f2bf(siluf_(y));
}

// ---------------- chunked (WY) gated delta rule, MFMA ----------------
// grid = B*H*8 = 128 blocks (v-slice of 64), block = 256 threads (4 waves).
// Chunk C=64. Within chunk (G = inclusive cumsum of g, all exp args <= 0):
//   A[i][s] = beta_i e^{G_i-G_s} (k_i.k_s)  (s<i),  U = beta*(V - Lam*K@S0)
//   delta = (I+A)^{-1} U  (blocked forward substitution)
//   O = diag(Lam) Q@S0 + P@delta,  P[i][s] = e^{G_i-G_s}(q_i.k_s) (s<=i)
//   S <- Lam_end*S + sum_s e^{G_end-G_s} k_s delta_s^T
// S kept fp32 in registers: wave w owns v-col range [16w,16w+16) (vj=w),
// Sacc[di] = tile rows dk=di*16+quad*4+r, col v=16w+lm (m89 C-layout).

#define SP 76   // row stride (bf16) of 64x64 LDS mats: 2-way-free b64 frag reads

__global__ __launch_bounds__(256) void delta_wy_kernel(const bf16* __restrict__ q,
                                                       const bf16* __restrict__ k,
                                                       const bf16* __restrict__ v,
                                                       const float* __restrict__ g,
                                                       const float* __restrict__ beta,
                                                       bf16* __restrict__ o) {
  __shared__ bf16 S0K[64 * SP];   // S0T-slice [v][dk_local] / KTt-slice [dk_local][s] (union)
  __shared__ bf16 Abf[64 * SP];   // A matrix bf16 [i][s]
  __shared__ bf16 Pm [64 * SP];   // P matrix bf16 [i][s]
  __shared__ bf16 DT [64 * SP];   // delta^T bf16 [v][s]
  __shared__ float Ub[64 * 64];   // U / residual workspace f32 [t][v]
  __shared__ float Gc[64], Lm[64], Bt[64], Ee[64];

  int blk = blockIdx.x;
  int vs = blk & 7, bh = blk >> 3;
  int b = bh >> 2, h = bh & 3;
  int tid = threadIdx.x;
  int wave = tid >> 6, lane = tid & 63;
  int lm = lane & 15, quad = lane >> 4;
  int v0 = vs * 64;

  const bf16* kb = k + (size_t)b * T_ * KDIM_ + h * DK_;
  const bf16* qb = q + (size_t)b * T_ * KDIM_ + h * DK_;
  const bf16* vb = v + (size_t)b * T_ * VDIM_ + h * DV_ + v0;
  bf16*       ob = o + (size_t)b * T_ * VDIM_ + h * DV_ + v0;
  const float* gbp = g    + (size_t)b * T_ * H_ + h;
  const float* bbp = beta + (size_t)b * T_ * H_ + h;

  f32x4 Sacc[16];
#pragma unroll
  for (int i = 0; i < 16; i++) Sacc[i] = (f32x4){0.f, 0.f, 0.f, 0.f};

  for (int c = 0; c < T_ / 64; c++) {
    int r0 = c * 64;

    // (a) decay/beta arrays + zero DT
    if (wave == 0) {
      float gv = gbp[(size_t)(r0 + lane) * H_];
      float bv = bbp[(size_t)(r0 + lane) * H_];
#pragma unroll
      for (int d = 1; d < 64; d <<= 1) {
        float nn = __shfl_up(gv, (unsigned)d, 64);
        if (lane >= d) gv += nn;
      }
      float g63 = __shfl(gv, 63, 64);
      Gc[lane] = gv; Lm[lane] = expf(gv); Bt[lane] = bv; Ee[lane] = expf(g63 - gv);
    }
    {
      int* dz = (int*)DT;
#pragma unroll
      for (int i = 0; i < 10; i++) {
        int idx = tid + 256 * i;
        if (idx < 64 * SP / 2) dz[idx] = 0;
      }
    }
    f32x4 Uacc[4], Oacc[4];
#pragma unroll
    for (int i = 0; i < 4; i++) { Uacc[i] = (f32x4){0.f,0.f,0.f,0.f}; Oacc[i] = (f32x4){0.f,0.f,0.f,0.f}; }
    __syncthreads();

    // (b,c) KK -> Abf, QK -> Pm (global-direct frags; B frags shared)
    {
      f32x4 akk[4], aqk[4];
#pragma unroll
      for (int j = 0; j < 4; j++) { akk[j] = (f32x4){0.f,0.f,0.f,0.f}; aqk[j] = (f32x4){0.f,0.f,0.f,0.f}; }
      const bf16* krow = kb + (size_t)(r0 + 16 * wave + lm) * KDIM_;
      const bf16* qrow = qb + (size_t)(r0 + 16 * wave + lm) * KDIM_;
#pragma unroll
      for (int ks = 0; ks < 8; ks++) {
        short8 ak = *(const short8*)(krow + 8 * quad + 32 * ks);
        short8 aq = *(const short8*)(qrow + 8 * quad + 32 * ks);
#pragma unroll
        for (int j = 0; j < 4; j++) {
          short8 bk = *(const short8*)(kb + (size_t)(r0 + 16 * j + lm) * KDIM_ + 8 * quad + 32 * ks);
          akk[j] = __builtin_amdgcn_mfma_f32_16x16x32_bf16(ak, bk, akk[j], 0, 0, 0);
          aqk[j] = __builtin_amdgcn_mfma_f32_16x16x32_bf16(aq, bk, aqk[j], 0, 0, 0);
        }
      }
      float gi[4], bi[4];
#pragma unroll
      for (int r = 0; r < 4; r++) {
        int i = 16 * wave + 4 * quad + r;
        gi[r] = Gc[i]; bi[r] = Bt[i];
      }
#pragma unroll
      for (int j = 0; j < 4; j++) {
        int s = 16 * j + lm;
        float gs = Gc[s];
#pragma unroll
        for (int r = 0; r < 4; r++) {
          int i = 16 * wave + 4 * quad + r;
          float dec = expf(gi[r] - gs);
          Abf[(size_t)i * SP + s] = f2bf((s < i)  ? bi[r] * dec * akk[j][r] : 0.f);
          Pm [(size_t)i * SP + s] = f2bf((s <= i) ? dec * aqk[j][r]        : 0.f);
        }
      }
    }
    __syncthreads();

    // (d) S0T slice passes: KS0 -> Uacc, QS0 -> Oacc
#pragma unroll
    for (int p = 0; p < 4; p++) {
#pragma unroll
      for (int di2 = 0; di2 < 4; di2++)
        st4bf(&S0K[(size_t)(16 * wave + lm) * SP + 16 * di2 + 4 * quad], Sacc[4 * p + di2]);
      __syncthreads();
#pragma unroll
      for (int ks = 0; ks < 2; ks++) {
        short8 bs = ld76(&S0K[(size_t)(16 * wave + lm) * SP + 8 * quad + 32 * ks]);
#pragma unroll
        for (int ti = 0; ti < 4; ti++) {
          short8 ak = *(const short8*)(kb + (size_t)(r0 + 16 * ti + lm) * KDIM_ + 64 * p + 8 * quad + 32 * ks);
          short8 aq = *(const short8*)(qb + (size_t)(r0 + 16 * ti + lm) * KDIM_ + 64 * p + 8 * quad + 32 * ks);
          Uacc[ti] = __builtin_amdgcn_mfma_f32_16x16x32_bf16(ak, bs, Uacc[ti], 0, 0, 0);
          Oacc[ti] = __builtin_amdgcn_mfma_f32_16x16x32_bf16(aq, bs, Oacc[ti], 0, 0, 0);
        }
      }
      __syncthreads();
    }

    // (e) U epilogue + pre-scale Oacc by Lam
#pragma unroll
    for (int ti = 0; ti < 4; ti++)
#pragma unroll
      for (int r = 0; r < 4; r++) {
        int t = 16 * ti + 4 * quad + r;
        float lam = Lm[t], bet = Bt[t];
        float vg = bf2f(vb[(size_t)(r0 + t) * VDIM_ + 16 * wave + lm]);
        Ub[t * 64 + 16 * wave + lm] = bet * (vg - lam * Uacc[ti][r]);
        Oacc[ti][r] *= lam;
      }
    __syncthreads();

    // (f) blocked forward substitution: delta = (I+A)^{-1} U
#pragma unroll
    for (int j = 0; j < 4; j++) {
      if (j > 0) {
        f32x4 racc = (f32x4){0.f, 0.f, 0.f, 0.f};
        int nk = (j == 3) ? 2 : 1;
        for (int ks = 0; ks < nk; ks++) {
          short8 aa = ld76(&Abf[(size_t)(16 * j + lm) * SP + 8 * quad + 32 * ks]);
          short8 bd = ld76(&DT [(size_t)(16 * wave + lm) * SP + 8 * quad + 32 * ks]);
          racc = __builtin_amdgcn_mfma_f32_16x16x32_bf16(aa, bd, racc, 0, 0, 0);
        }
#pragma unroll
        for (int r = 0; r < 4; r++)
          Ub[(16 * j + 4 * quad + r) * 64 + 16 * wave + lm] -= racc[r];
        __syncthreads();
      }
      if (wave == 0) {
        int tl = lane & 15, sg = lane >> 4;
        short4v ab4 = *(const short4v*)&Abf[(size_t)(16 * j + tl) * SP + 16 * j + 4 * sg];
        float av[4];
        av[0] = bf2f((bf16)ab4[0]); av[1] = bf2f((bf16)ab4[1]);
        av[2] = bf2f((bf16)ab4[2]); av[3] = bf2f((bf16)ab4[3]);
        float d[16];
#pragma unroll
        for (int t = 0; t < 16; t++) {
          float val = Ub[(16 * j + t) * 64 + lane];
#pragma unroll
          for (int s = 0; s < t; s++) {
            float ats = __shfl(av[s & 3], t + 16 * (s >> 2), 64);
            val -= ats * d[s];
          }
          d[t] = val;
          DT[(size_t)lane * SP + 16 * j + t] = f2bf(val);
        }
      }
      __syncthreads();
    }

    // (g) O = Lam*QS0 + P@delta, store
#pragma unroll
    for (int ks = 0; ks < 2; ks++) {
      short8 bd = ld76(&DT[(size_t)(16 * wave + lm) * SP + 8 * quad + 32 * ks]);
#pragma unroll
      for (int ti = 0; ti < 4; ti++) {
        short8 ap = ld76(&Pm[(size_t)(16 * ti + lm) * SP + 8 * quad + 32 * ks]);
        Oacc[ti] = __builtin_amdgcn_mfma_f32_16x16x32_bf16(ap, bd, Oacc[ti], 0, 0, 0);
      }
    }
#pragma unroll
    for (int ti = 0; ti < 4; ti++)
#pragma unroll
      for (int r = 0; r < 4; r++) {
        int t = 16 * ti + 4 * quad + r;
        ob[(size_t)(r0 + t) * VDIM_ + 16 * wave + lm] = f2bf(Oacc[ti][r]);
      }

    // (h) S *= Lam_end
    {
      float lend = Lm[63];
#pragma unroll
      for (int i = 0; i < 16; i++) {
        Sacc[i][0] *= lend; Sacc[i][1] *= lend; Sacc[i][2] *= lend; Sacc[i][3] *= lend;
      }
    }

    // (i) S += sum_s e^{Gend-Gs} k_s delta_s^T  (4 dk-slice passes)
#pragma unroll
    for (int p = 0; p < 4; p++) {
      __syncthreads();   // guard S0K overwrite vs previous reads
      {
        int s = lane, dg = wave;
        float e = Ee[s];
        const bf16* kr = kb + (size_t)(r0 + s) * KDIM_ + 64 * p + 16 * dg;
#pragma unroll
        for (int u = 0; u < 4; u++) {
          short4v kv4 = *(const short4v*)(kr + 4 * u);
#pragma unroll
          for (int cc = 0; cc < 4; cc++)
            S0K[(size_t)(16 * dg + 4 * u + cc) * SP + s] = f2bf(bf2f((bf16)kv4[cc]) * e);
        }
      }
      __syncthreads();
#pragma unroll
      for (int ks = 0; ks < 2; ks++) {
        short8 bd = ld76(&DT[(size_t)(16 * wave + lm) * SP + 8 * quad + 32 * ks]);
#pragma unroll
        for (int di2 = 0; di2 < 4; di2++) {
          short8 akt = ld76(&S0K[(size_t)(16 * di2 + lm) * SP + 8 * quad + 32 * ks]);
          Sacc[4 * p + di2] = __builtin_amdgcn_mfma_f32_16x16x32_bf16(akt, bd, Sacc[4 * p + di2], 0, 0, 0);
        }
      }
    }
    __syncthreads();   // end-of-chunk: DT/S0K reused next chunk
  }
}

// ---------------- gated RMSNorm (in place, bf16) ----------------

__global__ __launch_bounds__(256) void gated_rms_kernel(bf16* __restrict__ o,
                                                        const bf16* __restrict__ gate,
                                                        const float* __restrict__ onw) {
  __shared__ float red[4];
  int blk = blockIdx.x;
  int h = blk & 3;
  int bt = blk >> 2;
  size_t base = (size_t)bt * VDIM_ + h * DV_;
  int tid = threadIdx.x;
  float o1 = bf2f(o[base + tid]), o2 = bf2f(o[base + tid + 256]);
  float ss = block_sum256(o1 * o1 + o2 * o2, red);
  float s = rsqrtf(ss * (1.f / DV_) + 1e-5f);
  float g1 = bf2f(gate[base + tid]), g2 = bf2f(gate[base + tid + 256]);
  o[base + tid]       = f2bf(o1 * s * onw[tid] * siluf_(g1));
  o[base + tid + 256] = f2bf(o2 * s * onw[tid + 256] * siluf_(g2));
}

// ---------------- launch ----------------

extern "C" void kernel_launch(void* const* d_in, const int* in_sizes, int n_in,
                              void* d_out, int out_size, void* d_ws, size_t ws_size,
                              hipStream_t stream) {
  const float* x        = (const float*)d_in[0];
  const float* Wq       = (const float*)d_in[1];
  const float* Wk       = (const float*)d_in[2];
  const float* Wv       = (const float*)d_in[3];
  const float* Wa       = (const float*)d_in[4];
  const float* Wb       = (const float*)d_in[5];
  const float* Wg       = (const float*)d_in[6];
  const float* conv_q_w = (const float*)d_in[7];
  const float* conv_k_w = (const float*)d_in[8];
  const float* conv_v_w = (const float*)d_in[9];
  const float* A_log    = (const float*)d_in[10];
  const float* dt_bias  = (const float*)d_in[11];
  const float* o_norm_w = (const float*)d_in[12];
  const float* Wo       = (const float*)d_in[13];
  const float* ln1_w    = (const float*)d_in[14];
  const float* ln1_b    = (const float*)d_in[15];
  const float* ln2_w    = (const float*)d_in[16];
  const float* ln2_b    = (const float*)d_in[17];
  const float* ffn_w1   = (const float*)d_in[18];
  const float* ffn_b1   = (const float*)d_in[19];
  const float* ffn_w2   = (const float*)d_in[20];
  const float* ffn_b2   = (const float*)d_in[21];

  size_t required = (size_t)218 << 20;
  if (ws_size < required) {
    sentinel_kernel<<<(out_size + 255) / 256, 256, 0, stream>>>((float*)d_out, out_size);
    return;
  }

  char* base = (char*)d_ws;
  float* pre    = (float*)(base);                        // 64MB scratch
  bf16*  normed = (bf16*)(base + ((size_t)64  << 20));   // 16MB
  bf16*  q16    = (bf16*)(base + ((size_t)80  << 20));   // 16MB
  bf16*  k16    = (bf16*)(base + ((size_t)96  << 20));   // 16MB
  bf16*  v16    = (bf16*)(base + ((size_t)112 << 20));   // 32MB
  bf16*  g16    = (bf16*)(base + ((size_t)144 << 20));   // 32MB
  bf16*  o16    = (bf16*)(base + ((size_t)176 << 20));   // 32MB
  bf16*  wslot  = (bf16*)(base + ((size_t)208 << 20));   // 8MB JIT weight slot
  float* gvec   = (float*)(base + ((size_t)216 << 20));  // 128KB
  float* bvec   = gvec + (size_t)BT_ * H_;
  float* x2     = (float*)(base);
  bf16*  hb16   = (bf16*)(base + ((size_t)64  << 20));
  bf16*  ffn1   = (bf16*)(base + ((size_t)80  << 20));

  // 1) LN1 -> bf16
  ln_kernel<<<BT_, 256, 0, stream>>>(x, ln1_w, ln1_b, normed);

  // 2) projections + convs
  convT_kernel<<<dim3(KDIM_ / 32, D_ / 32), 256, 0, stream>>>(Wq, wslot, D_, KDIM_);
  gemm_mfma<float><<<dim3(KDIM_ / 128, BT_ / 128), 256, 0, stream>>>(normed, wslot, nullptr, nullptr, pre, KDIM_, D_, 0);
  conv_qk_kernel<<<BT_ * H_, 256, 0, stream>>>(pre, conv_q_w, q16, 0.0625f);

  convT_kernel<<<dim3(KDIM_ / 32, D_ / 32), 256, 0, stream>>>(Wk, wslot, D_, KDIM_);
  gemm_mfma<float><<<dim3(KDIM_ / 128, BT_ / 128), 256, 0, stream>>>(normed, wslot, nullptr, nullptr, pre, KDIM_, D_, 0);
  conv_qk_kernel<<<BT_ * H_, 256, 0, stream>>>(pre, conv_k_w, k16, 1.0f);

  convT_kernel<<<dim3(VDIM_ / 32, D_ / 32), 256, 0, stream>>>(Wv, wslot, D_, VDIM_);
  gemm_mfma<float><<<dim3(VDIM_ / 128, BT_ / 128), 256, 0, stream>>>(normed, wslot, nullptr, nullptr, pre, VDIM_, D_, 0);
  conv_v_kernel<<<(BT_ * VDIM_) / 256, 256, 0, stream>>>(pre, conv_v_w, v16);

  convT_kernel<<<dim3(VDIM_ / 32, D_ / 32), 256, 0, stream>>>(Wg, wslot, D_, VDIM_);
  gemm_mfma<bf16><<<dim3(VDIM_ / 128, BT_ / 128), 256, 0, stream>>>(normed, wslot, nullptr, nullptr, g16, VDIM_, D_, 0);

  ab_kernel<<<BT_, 256, 0, stream>>>(normed, Wa, Wb, A_log, dt_bias, gvec, bvec);

  // 3) gated delta rule (chunked WY, MFMA)
  delta_wy_kernel<<<B_ * H_ * 8, 256, 0, stream>>>(q16, k16, v16, gvec, bvec, o16);

  // 4) gated RMSNorm (in place)
  gated_rms_kernel<<<BT_ * H_, 256, 0, stream>>>(o16, g16, o_norm_w);

  // 5) x2 = x + o @ Wo
  convT_kernel<<<dim3(D_ / 32, VDIM_ / 32), 256, 0, stream>>>(Wo, wslot, VDIM_, D_);
  gemm_mfma<float><<<dim3(D_ / 128, BT_ / 128), 256, 0, stream>>>(o16, wslot, nullptr, x, x2, D_, VDIM_, 4);

  // 6) LN2 -> bf16
  ln_kernel<<<BT_, 256, 0, stream>>>(x2, ln2_w, ln2_b, hb16);

  // 7) FFN
  convT_kernel<<<dim3(FFN_ / 32, D_ / 32), 256, 0, stream>>>(ffn_w1, wslot, D_, FFN_);
  gemm_mfma<bf16><<<dim3(FFN_ / 128, BT_ / 128), 256, 0, stream>>>(hb16, wslot, ffn_b1, nullptr, ffn1, FFN_, D_, 1 | 2);
  convT_kernel<<<dim3(D_ / 32, FFN_ / 32), 256, 0, stream>>>(ffn_w2, wslot, FFN_, D_);
  gemm_mfma<float><<<dim3(D_ / 128, BT_ / 128), 256, 0, stream>>>(ffn1, wslot, ffn_b2, x2, (float*)d_out, D_, FFN_, 1 | 4);
}

// Round 6
// 1293.461 us; speedup vs baseline: 5.4900x; 1.3653x over previous
//
#include <hip/hip_runtime.h>
#include <math.h>

#define B_    4
#define T_    2048
#define D_    1024
#define H_    4
#define DK_   256
#define DV_   512
#define KDIM_ 1024
#define VDIM_ 2048
#define FFN_  4096
#define BT_   8192   // B_*T_

typedef unsigned short bf16;
typedef __attribute__((ext_vector_type(8))) short short8;   // MFMA A/B frag (8 bf16)
typedef __attribute__((ext_vector_type(4))) short short4v;  // 4 bf16
typedef __attribute__((ext_vector_type(4))) float f32x4;    // MFMA C/D frag

// ---------------- helpers ----------------

__device__ __forceinline__ float sigmoidf_(float x) { return 1.f / (1.f + expf(-x)); }
__device__ __forceinline__ float siluf_(float x)    { return x / (1.f + expf(-x)); }
__device__ __forceinline__ float geluf_(float x)    { return 0.5f * x * (1.f + erff(x * 0.70710678118654752f)); }

__device__ __forceinline__ float bf2f(bf16 u) {
  union { unsigned int i; float f; } c; c.i = (unsigned int)u << 16; return c.f;
}
__device__ __forceinline__ bf16 f2bf(float f) {
  union { unsigned int i; float f; } c; c.f = f;
  unsigned int r = c.i + 0x7fffu + ((c.i >> 16) & 1u);   // RNE
  return (bf16)(r >> 16);
}

// async global->LDS, 16B per lane
__device__ __forceinline__ void gload16(const bf16* g, bf16* l) {
  __builtin_amdgcn_global_load_lds((__attribute__((address_space(1))) const void*)g,
                                   (__attribute__((address_space(3))) void*)l, 16, 0, 0);
}

__device__ __forceinline__ void storeC(float* p, float v) { *p = v; }
__device__ __forceinline__ void storeC(bf16* p, float v)  { *p = f2bf(v); }

// load 8 bf16 from an 8B-aligned LDS address as two b64s
__device__ __forceinline__ short8 ld76(const bf16* p) {
  union { short8 v; short4v h[2]; } u;
  u.h[0] = *(const short4v*)p;
  u.h[1] = *(const short4v*)(p + 4);
  return u.v;
}
// pack f32x4 -> 4 bf16, 8B store
__device__ __forceinline__ void st4bf(bf16* p, f32x4 v) {
  short4v o;
  o[0] = (short)f2bf(v[0]); o[1] = (short)f2bf(v[1]);
  o[2] = (short)f2bf(v[2]); o[3] = (short)f2bf(v[3]);
  *(short4v*)p = o;
}

__device__ __forceinline__ float block_sum256(float v, float* red) {
#pragma unroll
  for (int off = 32; off; off >>= 1) v += __shfl_xor(v, off, 64);
  __syncthreads();
  if ((threadIdx.x & 63) == 0) red[threadIdx.x >> 6] = v;
  __syncthreads();
  return red[0] + red[1] + red[2] + red[3];
}

// ---------------- diagnostic sentinel (ws too small) ----------------

__global__ __launch_bounds__(256) void sentinel_kernel(float* out, int n) {
  int i = blockIdx.x * 256 + threadIdx.x;
  if (i < n) out[i] = 12345.0f;
}

// ---------------- LayerNorm -> bf16 ----------------

__global__ __launch_bounds__(256) void ln_kernel(const float* __restrict__ x,
                                                 const float* __restrict__ w,
                                                 const float* __restrict__ b,
                                                 bf16* __restrict__ y) {
  __shared__ float red[4];
  int row = blockIdx.x;
  const float* xr = x + (size_t)row * D_;
  float xv[4];
  float s = 0.f;
#pragma unroll
  for (int i = 0; i < 4; i++) { xv[i] = xr[threadIdx.x + 256 * i]; s += xv[i]; }
  float mean = block_sum256(s, red) * (1.f / D_);
  float s2 = 0.f;
#pragma unroll
  for (int i = 0; i < 4; i++) { float d = xv[i] - mean; s2 += d * d; }
  float var = block_sum256(s2, red) * (1.f / D_);
  float inv = rsqrtf(var + 1e-5f);
  bf16* yr = y + (size_t)row * D_;
#pragma unroll
  for (int i = 0; i < 4; i++) {
    int c = threadIdx.x + 256 * i;
    yr[c] = f2bf((xv[i] - mean) * inv * w[c] + b[c]);
  }
}

// ---------------- weight convert+transpose: fp32 [K][N] -> bf16 [N][K] ----------------

__global__ __launch_bounds__(256) void convT_kernel(const float* __restrict__ src,
                                                    bf16* __restrict__ dst,
                                                    int K, int N) {
  __shared__ float t[32][33];
  int n0 = blockIdx.x * 32, k0 = blockIdx.y * 32;
  int tx = threadIdx.x & 31, ty = threadIdx.x >> 5;
#pragma unroll
  for (int i = 0; i < 4; i++)
    t[ty + i * 8][tx] = src[(size_t)(k0 + ty + i * 8) * N + n0 + tx];
  __syncthreads();
#pragma unroll
  for (int i = 0; i < 4; i++)
    dst[(size_t)(n0 + ty + i * 8) * K + k0 + tx] = f2bf(t[tx][ty + i * 8]);
}

// ---------------- k transpose per head: k16 [b][t][h*DK+dk] -> kT [bh][dk][t] ----------------

__global__ __launch_bounds__(256) void kT_kernel(const bf16* __restrict__ k16,
                                                 bf16* __restrict__ kT) {
  __shared__ bf16 tile[32][34];
  int t0 = blockIdx.x * 32;
  int d0 = blockIdx.y * 32;
  int bh = blockIdx.z;
  int b = bh >> 2, h = bh & 3;
  int tx = threadIdx.x & 31, ty = threadIdx.x >> 5;
#pragma unroll
  for (int i = 0; i < 4; i++)
    tile[ty + 8 * i][tx] = k16[(size_t)(b * T_ + t0 + ty + 8 * i) * KDIM_ + h * DK_ + d0 + tx];
  __syncthreads();
#pragma unroll
  for (int i = 0; i < 4; i++)
    kT[((size_t)bh * DK_ + d0 + ty + 8 * i) * T_ + t0 + tx] = tile[tx][ty + 8 * i];
}

// ---------------- bf16 MFMA GEMM (unchanged from R3) ----------------

template <typename TC>
__global__ __launch_bounds__(256) void gemm_mfma(const bf16* __restrict__ A,
                                                 const bf16* __restrict__ Bt,
                                                 const float* __restrict__ bias,
                                                 const float* __restrict__ res,
                                                 TC* __restrict__ C,
                                                 int N, int K, int flags) {
  __shared__ __align__(16) bf16 As[128 * 32];
  __shared__ __align__(16) bf16 Bs[128 * 32];
  int tid = threadIdx.x;
  int wave = tid >> 6, lane = tid & 63;
  int bm = blockIdx.y * 128, bn = blockIdx.x * 128;
  int wm = (wave >> 1) * 64, wn = (wave & 1) * 64;
  int lm = lane & 15;
  int quad = lane >> 4;

  f32x4 acc[4][4];
#pragma unroll
  for (int i = 0; i < 4; i++)
#pragma unroll
    for (int j = 0; j < 4; j++) acc[i][j] = (f32x4){0.f, 0.f, 0.f, 0.f};

  int srow = wave * 32 + (lane >> 2);
  int scol = (lane & 3) * 8;
  const bf16* ag = A  + (size_t)(bm + srow) * K + scol;
  const bf16* bg = Bt + (size_t)(bn + srow) * K + scol;
  bf16* al = As + wave * 32 * 32;
  bf16* bl = Bs + wave * 32 * 32;
  const size_t gstep = (size_t)16 * K;

  for (int k0 = 0; k0 < K; k0 += 32) {
    gload16(ag + k0,         al);
    gload16(ag + k0 + gstep, al + 16 * 32);
    gload16(bg + k0,         bl);
    gload16(bg + k0 + gstep, bl + 16 * 32);
    __syncthreads();

    short8 af[4], bf[4];
#pragma unroll
    for (int i = 0; i < 4; i++)
      af[i] = *(const short8*)&As[(wm + i * 16 + lm) * 32 + quad * 8];
#pragma unroll
    for (int j = 0; j < 4; j++)
      bf[j] = *(const short8*)&Bs[(wn + j * 16 + lm) * 32 + quad * 8];
#pragma unroll
    for (int i = 0; i < 4; i++)
#pragma unroll
      for (int j = 0; j < 4; j++)
        acc[i][j] = __builtin_amdgcn_mfma_f32_16x16x32_bf16(af[i], bf[j], acc[i][j], 0, 0, 0);
    __syncthreads();
  }

#pragma unroll
  for (int i = 0; i < 4; i++) {
    int row0 = bm + wm + i * 16 + quad * 4;
#pragma unroll
    for (int j = 0; j < 4; j++) {
      int col = bn + wn + j * 16 + lm;
      float badd = (flags & 1) ? bias[col] : 0.f;
#pragma unroll
      for (int r = 0; r < 4; r++) {
        float v = acc[i][j][r] + badd;
        if (flags & 2) v = geluf_(v);
        if (flags & 4) v += res[(size_t)(row0 + r) * N + col];
        storeC(&C[(size_t)(row0 + r) * N + col], v);
      }
    }
  }
}

// ---------------- fused Wa/Wb projections -> g, beta ----------------

__global__ __launch_bounds__(256) void ab_kernel(const bf16* __restrict__ normed,
                                                 const float* __restrict__ Wa,
                                                 const float* __restrict__ Wb,
                                                 const float* __restrict__ A_log,
                                                 const float* __restrict__ dt_bias,
                                                 float* __restrict__ g,
                                                 float* __restrict__ beta) {
  __shared__ float red[4];
  int row = blockIdx.x;
  const bf16* xr = normed + (size_t)row * D_;
  float aacc[4] = {}, bacc[4] = {};
#pragma unroll
  for (int i = 0; i < 4; i++) {
    int d = threadIdx.x + 256 * i;
    float xv = bf2f(xr[d]);
    float4 wa = *(const float4*)&Wa[d * 4];
    float4 wb = *(const float4*)&Wb[d * 4];
    aacc[0] += xv * wa.x; aacc[1] += xv * wa.y; aacc[2] += xv * wa.z; aacc[3] += xv * wa.w;
    bacc[0] += xv * wb.x; bacc[1] += xv * wb.y; bacc[2] += xv * wb.z; bacc[3] += xv * wb.w;
  }
  float sa[4], sb[4];
#pragma unroll
  for (int h = 0; h < 4; h++) {
    sa[h] = block_sum256(aacc[h], red);
    sb[h] = block_sum256(bacc[h], red);
  }
  if (threadIdx.x < 4) {
    int h = threadIdx.x;
    float xa = sa[h] + dt_bias[h];
    float sp = (xa > 20.f) ? xa : log1pf(expf(xa));
    g[row * 4 + h] = -expf(A_log[h]) * sp;
    beta[row * 4 + h] = sigmoidf_(sb[h]);
  }
}

// ---------------- causal conv(4) + SiLU (+ L2 norm for q/k) ----------------

__global__ __launch_bounds__(256) void conv_qk_kernel(const float* __restrict__ pre,
                                                      const float* __restrict__ convw,
                                                      bf16* __restrict__ out,
                                                      float scale) {
  __shared__ float red[4];
  int blk = blockIdx.x;
  int h = blk & 3;
  int bt = blk >> 2;
  int t = bt & (T_ - 1);
  int c = h * DK_ + threadIdx.x;
  float y = 0.f;
#pragma unroll
  for (int i = 0; i < 4; i++) {
    int tt = t + i - 3;
    if (tt >= 0) y += pre[(size_t)(bt + i - 3) * KDIM_ + c] * convw[c * 4 + i];
  }
  y = siluf_(y);
  float ss = block_sum256(y * y, red);
  y *= rsqrtf(ss + 1e-6f) * scale;
  out[(size_t)bt * KDIM_ + c] = f2bf(y);
}

__global__ __launch_bounds__(256) void conv_v_kernel(const float* __restrict__ pre,
                                                     const float* __restrict__ convw,
                                                     bf16* __restrict__ out) {
  int idx = blockIdx.x * 256 + threadIdx.x;
  int c = idx & (VDIM_ - 1);
  int bt = idx >> 11;
  int t = bt & (T_ - 1);
  float y = 0.f;
#pragma unroll
  for (int i = 0; i < 4; i++) {
    int tt = t + i - 3;
    if (tt >= 0) y += pre[(size_t)(bt + i - 3) * VDIM_ + c] * convw[c * 4 + i];
  }
  out[idx] = f2bf(siluf_(y));
}

// ---------------- delta rule phase 1 (parallel over bh x chunk) ----------------
// Per (bh, chunk): A[i][s]=beta_i e^{Gi-Gs}(ki.ks) (s<i); P[i][s]=e^{Gi-Gs}(qi.ks) (s<=i)
// -> Pg.  Solve (I+A) [W|Y] = [beta*V | beta*Lam*K]  -> Wg [64x512], Yg [64x256].
// Store Gc -> gsc.  No dependence on S: fully parallel (512 blocks).

#define SP 76

__global__ __launch_bounds__(256, 2) void delta_p1(const bf16* __restrict__ q,
                                                   const bf16* __restrict__ k,
                                                   const bf16* __restrict__ v,
                                                   const float* __restrict__ g,
                                                   const float* __restrict__ beta,
                                                   bf16* __restrict__ Pg,
                                                   bf16* __restrict__ Wg,
                                                   bf16* __restrict__ Yg,
                                                   float* __restrict__ gsc) {
  __shared__ bf16 Abf[64 * SP];
  __shared__ bf16 DTg[64 * SP];
  __shared__ float Ub[64 * 64];
  __shared__ float Gc[64], Lm[64], Bt[64];

  int blk = blockIdx.x;
  int c = blk & 31, bh = blk >> 5;
  int b = bh >> 2, h = bh & 3;
  int tid = threadIdx.x;
  int wave = tid >> 6, lane = tid & 63;
  int lm = lane & 15, quad = lane >> 4;
  int r0 = c * 64;

  const bf16* kb = k + (size_t)b * T_ * KDIM_ + h * DK_;
  const bf16* qb = q + (size_t)b * T_ * KDIM_ + h * DK_;
  const bf16* vb = v + (size_t)b * T_ * VDIM_ + h * DV_;
  const float* gbp = g    + (size_t)b * T_ * H_ + h;
  const float* bbp = beta + (size_t)b * T_ * H_ + h;
  size_t cb = (size_t)bh * 32 + c;
  bf16* PgC = Pg + cb * 4096;
  bf16* WgC = Wg + cb * 64 * 512;
  bf16* YgC = Yg + cb * 64 * 256;

  // (a) cumsum of g -> Gc, Lam, beta
  if (wave == 0) {
    float gv = gbp[(size_t)(r0 + lane) * H_];
    float bv = bbp[(size_t)(r0 + lane) * H_];
#pragma unroll
    for (int d = 1; d < 64; d <<= 1) {
      float nn = __shfl_up(gv, (unsigned)d, 64);
      if (lane >= d) gv += nn;
    }
    Gc[lane] = gv; Lm[lane] = expf(gv); Bt[lane] = bv;
    gsc[cb * 64 + lane] = gv;
  }
  __syncthreads();

  // (b,c) KK^T -> Abf, QK^T -> Pg
  {
    f32x4 akk[4], aqk[4];
#pragma unroll
    for (int j = 0; j < 4; j++) { akk[j] = (f32x4){0.f,0.f,0.f,0.f}; aqk[j] = (f32x4){0.f,0.f,0.f,0.f}; }
    const bf16* krow = kb + (size_t)(r0 + 16 * wave + lm) * KDIM_;
    const bf16* qrow = qb + (size_t)(r0 + 16 * wave + lm) * KDIM_;
#pragma unroll
    for (int ks = 0; ks < 8; ks++) {
      short8 ak = *(const short8*)(krow + 8 * quad + 32 * ks);
      short8 aq = *(const short8*)(qrow + 8 * quad + 32 * ks);
#pragma unroll
      for (int j = 0; j < 4; j++) {
        short8 bk = *(const short8*)(kb + (size_t)(r0 + 16 * j + lm) * KDIM_ + 8 * quad + 32 * ks);
        akk[j] = __builtin_amdgcn_mfma_f32_16x16x32_bf16(ak, bk, akk[j], 0, 0, 0);
        aqk[j] = __builtin_amdgcn_mfma_f32_16x16x32_bf16(aq, bk, aqk[j], 0, 0, 0);
      }
    }
    float gi[4], bi[4];
#pragma unroll
    for (int r = 0; r < 4; r++) {
      int i = 16 * wave + 4 * quad + r;
      gi[r] = Gc[i]; bi[r] = Bt[i];
    }
#pragma unroll
    for (int j = 0; j < 4; j++) {
      int s = 16 * j + lm;
      float gs = Gc[s];
#pragma unroll
      for (int r = 0; r < 4; r++) {
        int i = 16 * wave + 4 * quad + r;
        float dec = expf(gi[r] - gs);
        Abf[(size_t)i * SP + s] = f2bf((s < i)  ? bi[r] * dec * akk[j][r] : 0.f);
        PgC[(size_t)i * 64 + s] = f2bf((s <= i) ? dec * aqk[j][r]        : 0.f);
      }
    }
  }

  // 12 column groups of 64: grp 0..7 -> W (RHS beta*V), grp 8..11 -> Y (RHS beta*Lam*K)
  for (int grp = 0; grp < 12; grp++) {
    __syncthreads();        // Abf ready (grp0) / prev DTg stores done
    {
      int* dz = (int*)DTg;
#pragma unroll
      for (int i = 0; i < 10; i++) {
        int idx = tid + 256 * i;
        if (idx < 64 * SP / 2) dz[idx] = 0;
      }
    }
    int cg = 16 * wave + lm;
#pragma unroll
    for (int ti = 0; ti < 4; ti++)
#pragma unroll
      for (int r = 0; r < 4; r++) {
        int t = 16 * ti + 4 * quad + r;
        float val;
        if (grp < 8) val = Bt[t] * bf2f(vb[(size_t)(r0 + t) * VDIM_ + grp * 64 + cg]);
        else         val = Bt[t] * Lm[t] * bf2f(kb[(size_t)(r0 + t) * KDIM_ + (grp - 8) * 64 + cg]);
        Ub[t * 64 + cg] = val;
      }
    __syncthreads();

    // forward substitution (verbatim R5 structure)
#pragma unroll
    for (int j = 0; j < 4; j++) {
      if (j > 0) {
        f32x4 racc = (f32x4){0.f, 0.f, 0.f, 0.f};
        int nk = (j == 3) ? 2 : 1;
        for (int ks = 0; ks < nk; ks++) {
          short8 aa = ld76(&Abf[(size_t)(16 * j + lm) * SP + 8 * quad + 32 * ks]);
          short8 bd = ld76(&DTg[(size_t)(16 * wave + lm) * SP + 8 * quad + 32 * ks]);
          racc = __builtin_amdgcn_mfma_f32_16x16x32_bf16(aa, bd, racc, 0, 0, 0);
        }
#pragma unroll
        for (int r = 0; r < 4; r++)
          Ub[(16 * j + 4 * quad + r) * 64 + 16 * wave + lm] -= racc[r];
        __syncthreads();
      }
      if (wave == 0) {
        int tl = lane & 15, sg = lane >> 4;
        short4v ab4 = *(const short4v*)&Abf[(size_t)(16 * j + tl) * SP + 16 * j + 4 * sg];
        float av[4];
        av[0] = bf2f((bf16)ab4[0]); av[1] = bf2f((bf16)ab4[1]);
        av[2] = bf2f((bf16)ab4[2]); av[3] = bf2f((bf16)ab4[3]);
        float d[16];
#pragma unroll
        for (int t = 0; t < 16; t++) {
          float val = Ub[(16 * j + t) * 64 + lane];
#pragma unroll
          for (int s = 0; s < t; s++) {
            float ats = __shfl(av[s & 3], t + 16 * (s >> 2), 64);
            val -= ats * d[s];
          }
          d[t] = val;
          DTg[(size_t)lane * SP + 16 * j + t] = f2bf(val);
        }
      }
      __syncthreads();
    }

    // store group to Wg / Yg (row-major [t][col])
#pragma unroll
    for (int ti = 0; ti < 4; ti++)
#pragma unroll
      for (int r = 0; r < 4; r++) {
        int t = 16 * ti + 4 * quad + r;
        bf16 val = DTg[(size_t)(16 * wave + lm) * SP + t];
        if (grp < 8) WgC[(size_t)t * 512 + grp * 64 + cg] = val;
        else         YgC[(size_t)t * 256 + (grp - 8) * 64 + cg] = val;
      }
  }
}

// ---------------- delta rule phase 2 (sequential chunks; 256 blocks) ----------------
// grid = bh(16) x v-slice(16 of 32 cols). Per chunk: delta = W - Y@S;
// O = Lam*(Q@S) + P@delta; S <- Lam_end*S + K^T (e*delta).
// Wave w: r2=w>>1 (dk half for S / row pair for t-GEMMs), ct=w&1 (v col-tile).

#define SP2 264
#define SD  72

__global__ __launch_bounds__(256, 2) void delta_p2(const bf16* __restrict__ q,
                                                   const bf16* __restrict__ kT,
                                                   const bf16* __restrict__ Wg,
                                                   const bf16* __restrict__ Yg,
                                                   const bf16* __restrict__ Pg,
                                                   const float* __restrict__ gsc,
                                                   bf16* __restrict__ o) {
  __shared__ bf16 ST[32 * SP2];    // S^T [v][dk] bf16
  __shared__ bf16 dT[32 * SD];     // delta^T [v][s]
  __shared__ bf16 dTe[32 * SD];    // (e*delta)^T [v][s]
  __shared__ float Gc[64];

  int blk = blockIdx.x;
  int vs = blk & 15, bh = blk >> 4;
  int b = bh >> 2, h = bh & 3;
  int tid = threadIdx.x;
  int wave = tid >> 6, lane = tid & 63;
  int lm = lane & 15, quad = lane >> 4;
  int r2 = wave >> 1, ct = wave & 1;
  int v0 = vs * 32;

  const bf16* qb  = q  + (size_t)b * T_ * KDIM_ + h * DK_;
  const bf16* kTb = kT + (size_t)bh * DK_ * T_;
  bf16*       ob  = o  + (size_t)b * T_ * VDIM_ + h * DV_ + v0;

  f32x4 Sacc[8];
#pragma unroll
  for (int i = 0; i < 8; i++) Sacc[i] = (f32x4){0.f, 0.f, 0.f, 0.f};

  for (int c = 0; c < 32; c++) {
    int r0 = c * 64;
    size_t cb = (size_t)bh * 32 + c;
    const bf16* yc = Yg + cb * 64 * 256;
    const bf16* wc = Wg + cb * 64 * 512 + v0;
    const bf16* pc = Pg + cb * 4096;
    if (tid < 64) Gc[tid] = gsc[cb * 64 + tid];
    // stage S^T
#pragma unroll
    for (int di = 0; di < 8; di++)
      st4bf(&ST[(size_t)(16 * ct + lm) * SP2 + 16 * (8 * r2 + di) + 4 * quad], Sacc[di]);
    __syncthreads();

    short8 Bs[8];
#pragma unroll
    for (int kf = 0; kf < 8; kf++)
      Bs[kf] = *(const short8*)&ST[(size_t)(16 * ct + lm) * SP2 + 8 * quad + 32 * kf];

    f32x4 Yacc[2], Oacc[2];
#pragma unroll
    for (int i = 0; i < 2; i++) { Yacc[i] = (f32x4){0.f,0.f,0.f,0.f}; Oacc[i] = (f32x4){0.f,0.f,0.f,0.f}; }
#pragma unroll
    for (int i = 0; i < 2; i++) {
      int rt = 2 * r2 + i;
      const bf16* yrow = yc + (size_t)(16 * rt + lm) * 256;
      const bf16* qrow = qb + (size_t)(r0 + 16 * rt + lm) * KDIM_;
#pragma unroll
      for (int kf = 0; kf < 8; kf++) {
        short8 ya = *(const short8*)(yrow + 8 * quad + 32 * kf);
        short8 qa = *(const short8*)(qrow + 8 * quad + 32 * kf);
        Yacc[i] = __builtin_amdgcn_mfma_f32_16x16x32_bf16(ya, Bs[kf], Yacc[i], 0, 0, 0);
        Oacc[i] = __builtin_amdgcn_mfma_f32_16x16x32_bf16(qa, Bs[kf], Oacc[i], 0, 0, 0);
      }
    }
    float g63 = Gc[63];
#pragma unroll
    for (int i = 0; i < 2; i++) {
      int rt = 2 * r2 + i;
#pragma unroll
      for (int rr = 0; rr < 4; rr++) {
        int row = 16 * rt + 4 * quad + rr;
        float lam = expf(Gc[row]);
        float er  = expf(g63 - Gc[row]);
        float dv = bf2f(wc[(size_t)row * 512 + 16 * ct + lm]) - Yacc[i][rr];
        Oacc[i][rr] *= lam;
        dT [(size_t)(16 * ct + lm) * SD + row] = f2bf(dv);
        dTe[(size_t)(16 * ct + lm) * SD + row] = f2bf(dv * er);
      }
    }
    __syncthreads();

    // O += P@delta, store O
#pragma unroll
    for (int i = 0; i < 2; i++) {
      int rt = 2 * r2 + i;
      const bf16* prow = pc + (size_t)(16 * rt + lm) * 64;
#pragma unroll
      for (int kf = 0; kf < 2; kf++) {
        short8 pa = *(const short8*)(prow + 8 * quad + 32 * kf);
        short8 bd = *(const short8*)&dT[(size_t)(16 * ct + lm) * SD + 8 * quad + 32 * kf];
        Oacc[i] = __builtin_amdgcn_mfma_f32_16x16x32_bf16(pa, bd, Oacc[i], 0, 0, 0);
      }
#pragma unroll
      for (int rr = 0; rr < 4; rr++) {
        int row = 16 * rt + 4 * quad + rr;
        ob[(size_t)(r0 + row) * VDIM_ + 16 * ct + lm] = f2bf(Oacc[i][rr]);
      }
    }

    // S update
    float lend = expf(g63);
    short8 Be[2];
#pragma unroll
    for (int kf = 0; kf < 2; kf++)
      Be[kf] = *(const short8*)&dTe[(size_t)(16 * ct + lm) * SD + 8 * quad + 32 * kf];
#pragma unroll
    for (int di = 0; di < 8; di++) {
      int D = 8 * r2 + di;
      const bf16* krow = kTb + (size_t)(16 * D + lm) * T_ + r0;
      f32x4 s = Sacc[di];
      s[0] *= lend; s[1] *= lend; s[2] *= lend; s[3] *= lend;
#pragma unroll
      for (int kf = 0; kf < 2; kf++) {
        short8 ka = *(const short8*)(krow + 8 * quad + 32 * kf);
        s = __builtin_amdgcn_mfma_f32_16x16x32_bf16(ka, Be[kf], s, 0, 0, 0);
      }
      Sacc[di] = s;
    }
    __syncthreads();
  }
}

// ---------------- gated RMSNorm (in place, bf16) ----------------

__global__ __launch_bounds__(256) void gated_rms_kernel(bf16* __restrict__ o,
                                                        const bf16* __restrict__ gate,
                                                        const float* __restrict__ onw) {
  __shared__ float red[4];
  int blk = blockIdx.x;
  int h = blk & 3;
  int bt = blk >> 2;
  size_t base = (size_t)bt * VDIM_ + h * DV_;
  int tid = threadIdx.x;
  float o1 = bf2f(o[base + tid]), o2 = bf2f(o[base + tid + 256]);
  float ss = block_sum256(o1 * o1 + o2 * o2, red);
  float s = rsqrtf(ss * (1.f / DV_) + 1e-5f);
  float g1 = bf2f(gate[base + tid]), g2 = bf2f(gate[base + tid + 256]);
  o[base + tid]       = f2bf(o1 * s * onw[tid] * siluf_(g1));
  o[base + tid + 256] = f2bf(o2 * s * onw[tid + 256] * siluf_(g2));
}

// ---------------- launch ----------------

extern "C" void kernel_launch(void* const* d_in, const int* in_sizes, int n_in,
                              void* d_out, int out_size, void* d_ws, size_t ws_size,
                              hipStream_t stream) {
  const float* x        = (const float*)d_in[0];
  const float* Wq       = (const float*)d_in[1];
  const float* Wk       = (const float*)d_in[2];
  const float* Wv       = (const float*)d_in[3];
  const float* Wa       = (const float*)d_in[4];
  const float* Wb       = (const float*)d_in[5];
  const float* Wg       = (const float*)d_in[6];
  const float* conv_q_w = (const float*)d_in[7];
  const float* conv_k_w = (const float*)d_in[8];
  const float* conv_v_w = (const float*)d_in[9];
  const float* A_log    = (const float*)d_in[10];
  const float* dt_bias  = (const float*)d_in[11];
  const float* o_norm_w = (const float*)d_in[12];
  const float* Wo       = (const float*)d_in[13];
  const float* ln1_w    = (const float*)d_in[14];
  const float* ln1_b    = (const float*)d_in[15];
  const float* ln2_w    = (const float*)d_in[16];
  const float* ln2_b    = (const float*)d_in[17];
  const float* ffn_w1   = (const float*)d_in[18];
  const float* ffn_b1   = (const float*)d_in[19];
  const float* ffn_w2   = (const float*)d_in[20];
  const float* ffn_b2   = (const float*)d_in[21];

  size_t required = (size_t)218 << 20;
  if (ws_size < required) {
    sentinel_kernel<<<(out_size + 255) / 256, 256, 0, stream>>>((float*)d_out, out_size);
    return;
  }

  char* base = (char*)d_ws;
  float* pre    = (float*)(base);                        // 64MB scratch (proj outs)
  bf16*  normed = (bf16*)(base + ((size_t)64  << 20));   // 16MB
  bf16*  q16    = (bf16*)(base + ((size_t)80  << 20));   // 16MB
  bf16*  k16    = (bf16*)(base + ((size_t)96  << 20));   // 16MB
  bf16*  v16    = (bf16*)(base + ((size_t)112 << 20));   // 32MB
  bf16*  g16    = (bf16*)(base + ((size_t)144 << 20));   // 32MB
  bf16*  o16    = (bf16*)(base + ((size_t)176 << 20));   // 32MB
  bf16*  wslot  = (bf16*)(base + ((size_t)208 << 20));   // 8MB JIT weight slot
  float* gvec   = (float*)(base + ((size_t)216 << 20));  // 128KB
  float* bvec   = gvec + (size_t)BT_ * H_;               // 128KB
  float* gsc    = (float*)(base + ((size_t)217 << 20));  // 128KB
  // delta-phase buffers (pre region + normed region, dead after ab_kernel):
  bf16*  Yg     = (bf16*)(base);                         // 16MB  [0,16)
  bf16*  Wgb    = (bf16*)(base + ((size_t)16 << 20));    // 32MB  [16,48)
  bf16*  Pg     = (bf16*)(base + ((size_t)48 << 20));    // 4MB   [48,52)
  bf16*  kTg    = (bf16*)(base + ((size_t)52 << 20));    // 16MB  [52,68)
  // later reuses:
  float* x2     = (float*)(base);                        // 32MB (after delta)
  bf16*  hb16   = (bf16*)(base + ((size_t)64  << 20));
  bf16*  ffn1   = (bf16*)(base + ((size_t)80  << 20));

  // 1) LN1 -> bf16
  ln_kernel<<<BT_, 256, 0, stream>>>(x, ln1_w, ln1_b, normed);

  // 2) projections + convs
  convT_kernel<<<dim3(KDIM_ / 32, D_ / 32), 256, 0, stream>>>(Wq, wslot, D_, KDIM_);
  gemm_mfma<float><<<dim3(KDIM_ / 128, BT_ / 128), 256, 0, stream>>>(normed, wslot, nullptr, nullptr, pre, KDIM_, D_, 0);
  conv_qk_kernel<<<BT_ * H_, 256, 0, stream>>>(pre, conv_q_w, q16, 0.0625f);

  convT_kernel<<<dim3(KDIM_ / 32, D_ / 32), 256, 0, stream>>>(Wk, wslot, D_, KDIM_);
  gemm_mfma<float><<<dim3(KDIM_ / 128, BT_ / 128), 256, 0, stream>>>(normed, wslot, nullptr, nullptr, pre, KDIM_, D_, 0);
  conv_qk_kernel<<<BT_ * H_, 256, 0, stream>>>(pre, conv_k_w, k16, 1.0f);

  convT_kernel<<<dim3(VDIM_ / 32, D_ / 32), 256, 0, stream>>>(Wv, wslot, D_, VDIM_);
  gemm_mfma<float><<<dim3(VDIM_ / 128, BT_ / 128), 256, 0, stream>>>(normed, wslot, nullptr, nullptr, pre, VDIM_, D_, 0);
  conv_v_kernel<<<(BT_ * VDIM_) / 256, 256, 0, stream>>>(pre, conv_v_w, v16);

  convT_kernel<<<dim3(VDIM_ / 32, D_ / 32), 256, 0, stream>>>(Wg, wslot, D_, VDIM_);
  gemm_mfma<bf16><<<dim3(VDIM_ / 128, BT_ / 128), 256, 0, stream>>>(normed, wslot, nullptr, nullptr, g16, VDIM_, D_, 0);

  ab_kernel<<<BT_, 256, 0, stream>>>(normed, Wa, Wb, A_log, dt_bias, gvec, bvec);

  // 3) delta rule: kT transpose + parallel phase 1 + sequential phase 2
  kT_kernel<<<dim3(T_ / 32, DK_ / 32, 16), 256, 0, stream>>>(k16, kTg);
  delta_p1<<<512, 256, 0, stream>>>(q16, k16, v16, gvec, bvec, Pg, Wgb, Yg, gsc);
  delta_p2<<<256, 256, 0, stream>>>(q16, kTg, Wgb, Yg, Pg, gsc, o16);

  // 4) gated RMSNorm (in place)
  gated_rms_kernel<<<BT_ * H_, 256, 0, stream>>>(o16, g16, o_norm_w);

  // 5) x2 = x + o @ Wo
  convT_kernel<<<dim3(D_ / 32, VDIM_ / 32), 256, 0, stream>>>(Wo, wslot, VDIM_, D_);
  gemm_mfma<float><<<dim3(D_ / 128, BT_ / 128), 256, 0, stream>>>(o16, wslot, nullptr, x, x2, D_, VDIM_, 4);

  // 6) LN2 -> bf16
  ln_kernel<<<BT_, 256, 0, stream>>>(x2, ln2_w, ln2_b, hb16);

  // 7) FFN
  convT_kernel<<<dim3(FFN_ / 32, D_ / 32), 256, 0, stream>>>(ffn_w1, wslot, D_, FFN_);
  gemm_mfma<bf16><<<dim3(FFN_ / 128, BT_ / 128), 256, 0, stream>>>(hb16, wslot, ffn_b1, nullptr, ffn1, FFN_, D_, 1 | 2);
  convT_kernel<<<dim3(D_ / 32, FFN_ / 32), 256, 0, stream>>>(ffn_w2, wslot, FFN_, D_);
  gemm_mfma<float><<<dim3(D_ / 128, BT_ / 128), 256, 0, stream>>>(ffn1, wslot, ffn_b2, x2, (float*)d_out, D_, FFN_, 1 | 4);
}